// Round 2
// baseline (220.757 us; speedup 1.0000x reference)
//
#include <hip/hip_runtime.h>

#define NB 4
#define NN 2048
#define KK 32
#define DD 64
#define R2C 0.64f

// ---------------- prep: combined layer-0 weights ----------------
// w0x[j][c] = Wf[j][c] - Wf[128+j][c]      (x part, goes into bases)
// w0k[j][c] = Wf[64+j][c] + Wf[128+j][c]   (neighbor part, main kernel)
__global__ __launch_bounds__(256) void prep_w_kernel(const float* __restrict__ Wf,
                                                     float* __restrict__ w0x,
                                                     float* __restrict__ w0k) {
    int t = blockIdx.x * 256 + threadIdx.x;
    if (t < 64 * 32) {
        float a = Wf[t];
        float bk = Wf[64 * 32 + t];
        float dd = Wf[128 * 32 + t];
        w0x[t] = a - dd;
        w0k[t] = bk + dd;
    }
}

// ---------------- ball query ----------------
__global__ __launch_bounds__(256) void ball_query_kernel(const float* __restrict__ pos,
                                                         int* __restrict__ idx) {
    __shared__ float sp[NN * 3];
    __shared__ float sq[NN];
    int bb = blockIdx.x >> 3;
    int nbase = (blockIdx.x & 7) * 256;
    const float* pb = pos + bb * NN * 3;
    for (int i = threadIdx.x; i < NN * 3; i += 256) sp[i] = pb[i];
    __syncthreads();
    for (int i = threadIdx.x; i < NN; i += 256) {
        float px = sp[i * 3], py = sp[i * 3 + 1], pz = sp[i * 3 + 2];
        sq[i] = __fadd_rn(__fadd_rn(__fmul_rn(px, px), __fmul_rn(py, py)), __fmul_rn(pz, pz));
    }
    __syncthreads();

    int n = nbase + threadIdx.x;
    float qx = sp[n * 3], qy = sp[n * 3 + 1], qz = sp[n * 3 + 2];
    float sqn = sq[n];
    int* op = idx + (bb * NN + n) * KK;
    int cnt = 0;
    for (int m = 0; m < NN; ++m) {
        float mx = sp[m * 3], my = sp[m * 3 + 1], mz = sp[m * 3 + 2];
        float dot = __fadd_rn(__fadd_rn(__fmul_rn(qx, mx), __fmul_rn(qy, my)), __fmul_rn(qz, mz));
        float d2 = __fsub_rn(__fadd_rn(sqn, sq[m]), __fmul_rn(2.0f, dot));
        if (d2 < R2C) {
            op[cnt++] = m;
            if (cnt == KK) break;
        }
    }
    int first = op[0];
    for (; cnt < KK; ++cnt) op[cnt] = first;
}

// ---------------- per-query bases ----------------
__global__ __launch_bounds__(64) void bases_kernel(const float* __restrict__ x,
                                                   const float* __restrict__ w0x,
                                                   const float* __restrict__ W1,
                                                   const float* __restrict__ W2,
                                                   const float* __restrict__ Wl,
                                                   const float* __restrict__ bf,
                                                   const float* __restrict__ b1,
                                                   const float* __restrict__ b2,
                                                   const float* __restrict__ bl,
                                                   float* __restrict__ bases) {
    int q = blockIdx.x * 64 + threadIdx.x;
    const float4* xr = (const float4*)(x + (size_t)q * DD);
    float a0[32], a1[32], a2[32], a3[32];
#pragma unroll
    for (int c = 0; c < 32; ++c) { a0[c] = bf[c]; a1[c] = b1[c]; a2[c] = b2[c]; a3[c] = bl[c]; }
    for (int j0 = 0; j0 < 16; ++j0) {
        float4 xv = xr[j0];
        float xs[4] = {xv.x, xv.y, xv.z, xv.w};
#pragma unroll
        for (int jj = 0; jj < 4; ++jj) {
            int j = j0 * 4 + jj;
            float v = xs[jj];
#pragma unroll
            for (int c = 0; c < 32; ++c) {
                a0[c] = fmaf(v, w0x[j * 32 + c], a0[c]);
                a1[c] = fmaf(v, W1[(32 + j) * 32 + c], a1[c]);
                a2[c] = fmaf(v, W2[(64 + j) * 32 + c], a2[c]);
                a3[c] = fmaf(v, Wl[(96 + j) * 32 + c], a3[c]);
            }
        }
    }
    float* bq = bases + (size_t)q * 128;
    float4* b4 = (float4*)bq;
#pragma unroll
    for (int c = 0; c < 8; ++c) b4[c]      = make_float4(a0[4*c], a0[4*c+1], a0[4*c+2], a0[4*c+3]);
#pragma unroll
    for (int c = 0; c < 8; ++c) b4[8 + c]  = make_float4(a1[4*c], a1[4*c+1], a1[4*c+2], a1[4*c+3]);
#pragma unroll
    for (int c = 0; c < 8; ++c) b4[16 + c] = make_float4(a2[4*c], a2[4*c+1], a2[4*c+2], a2[4*c+3]);
#pragma unroll
    for (int c = 0; c < 8; ++c) b4[24 + c] = make_float4(a3[4*c], a3[4*c+1], a3[4*c+2], a3[4*c+3]);
}

// ---------------- helpers ----------------
__device__ __forceinline__ void load32(const float* __restrict__ p, float* h) {
#pragma unroll
    for (int c = 0; c < 8; ++c) {
        float4 v = ((const float4*)p)[c];
        h[4 * c] = v.x; h[4 * c + 1] = v.y; h[4 * c + 2] = v.z; h[4 * c + 3] = v.w;
    }
}

__device__ __forceinline__ void relu32(float* h) {
#pragma unroll
    for (int c = 0; c < 32; ++c) h[c] = fmaxf(h[c], 0.0f);
}

// scalar-path block: weights via wave-uniform global pointer (s_load, 16KB total -> sL1-resident)
__device__ __forceinline__ void mlp_block(const float* hin, const float* __restrict__ W, float* hacc) {
#pragma unroll
    for (int i = 0; i < 32; ++i) {
        float hv = hin[i];
#pragma unroll
        for (int c = 0; c < 32; ++c) hacc[c] = fmaf(hv, W[i * 32 + c], hacc[c]);
    }
}

// LDS-path block: wave-uniform ds_read_b128 broadcast
__device__ __forceinline__ void mlp_block_lds(const float* hin, const float* w, float* hacc) {
#pragma unroll
    for (int i = 0; i < 32; ++i) {
        float hv = hin[i];
#pragma unroll
        for (int c4 = 0; c4 < 8; ++c4) {
            float4 wv = *(const float4*)&w[i * 32 + c4 * 4];
            hacc[4 * c4 + 0] = fmaf(hv, wv.x, hacc[4 * c4 + 0]);
            hacc[4 * c4 + 1] = fmaf(hv, wv.y, hacc[4 * c4 + 1]);
            hacc[4 * c4 + 2] = fmaf(hv, wv.z, hacc[4 * c4 + 2]);
            hacc[4 * c4 + 3] = fmaf(hv, wv.w, hacc[4 * c4 + 3]);
        }
    }
}

__device__ __forceinline__ void st32(float* p, const float* h) {
#pragma unroll
    for (int c = 0; c < 8; ++c)
        ((float4*)p)[c] = make_float4(h[4 * c], h[4 * c + 1], h[4 * c + 2], h[4 * c + 3]);
}

// ---------------- main: per-(query,k) MLP + max over k ----------------
// Weight streams split across two HW paths:
//   LDS (16KB, broadcast ds_read_b128): w0k (8KB) + W2[0:64] (8KB)
//   scalar s_load (16KB, fits scalar L1): W1[0:32] (4KB) + Wl[0:96] (12KB)
__global__ __launch_bounds__(256, 2) void mlp_kernel(const float* __restrict__ x,
                                                     const int* __restrict__ idx,
                                                     const float* __restrict__ bases,
                                                     const float* __restrict__ w0k,
                                                     const float* __restrict__ W1,
                                                     const float* __restrict__ W2,
                                                     const float* __restrict__ Wl,
                                                     float* __restrict__ out) {
    __shared__ float lw[4096];   // [0:2048) = w0k, [2048:4096) = W2 rows 0..63
    {
        const float4* s0 = (const float4*)w0k;
        const float4* s2 = (const float4*)W2;
        float4* dst = (float4*)lw;
        for (int i = threadIdx.x; i < 512; i += 256) {
            dst[i] = s0[i];
            dst[512 + i] = s2[i];
        }
    }
    __syncthreads();

    int wave = blockIdx.x * 4 + (threadIdx.x >> 6);
    int lane = threadIdx.x & 63;
    int half = lane >> 5;
    int k = lane & 31;
    int q = wave * 2 + half;        // [0, 8192)
    int b = q >> 11;

    int nb = idx[q * KK + k];
    const float4* xr = (const float4*)(x + ((size_t)(b * NN + nb)) * DD);
    const float* bq = bases + (size_t)q * 128;

    // ---- layer 0: h0 = relu(base0 + sum_j xk[j] * w0k[j][c])  [LDS path] ----
    float h0[32];
    load32(bq, h0);
#pragma unroll 2
    for (int j0 = 0; j0 < 16; ++j0) {
        float4 xv = xr[j0];
        float xs[4] = {xv.x, xv.y, xv.z, xv.w};
#pragma unroll
        for (int jj = 0; jj < 4; ++jj) {
            int j = j0 * 4 + jj;
            float v = xs[jj];
#pragma unroll
            for (int c4 = 0; c4 < 8; ++c4) {
                float4 wv = *(const float4*)&lw[j * 32 + c4 * 4];
                h0[4 * c4 + 0] = fmaf(v, wv.x, h0[4 * c4 + 0]);
                h0[4 * c4 + 1] = fmaf(v, wv.y, h0[4 * c4 + 1]);
                h0[4 * c4 + 2] = fmaf(v, wv.z, h0[4 * c4 + 2]);
                h0[4 * c4 + 3] = fmaf(v, wv.w, h0[4 * c4 + 3]);
            }
        }
    }
    relu32(h0);

    // ---- layer 1: h1 = relu(base1 + h0 @ W1[0:32])  [scalar path] ----
    float h1[32];
    load32(bq + 32, h1);
    mlp_block(h0, W1, h1);
    relu32(h1);

    // ---- layer 2: h2 = relu(base2 + h1 @ W2[0:32] + h0 @ W2[32:64])  [LDS path] ----
    float h2[32];
    load32(bq + 64, h2);
    mlp_block_lds(h1, &lw[2048], h2);
    mlp_block_lds(h0, &lw[2048 + 1024], h2);
    relu32(h2);

    // ---- layer 3: h3 = base3 + h2 @ Wl[0:32] + h1 @ Wl[32:64] + h0 @ Wl[64:96]  [scalar path] ----
    float h3[32];
    load32(bq + 96, h3);
    mlp_block(h2, Wl, h3);
    mlp_block(h1, Wl + 32 * 32, h3);
    mlp_block(h0, Wl + 64 * 32, h3);

    // ---- max over k: 5-step butterfly within each 32-lane half ----
#pragma unroll
    for (int m = 1; m < 32; m <<= 1) {
#pragma unroll
        for (int c = 0; c < 32; ++c) h0[c] = fmaxf(h0[c], __shfl_xor(h0[c], m, 32));
#pragma unroll
        for (int c = 0; c < 32; ++c) h1[c] = fmaxf(h1[c], __shfl_xor(h1[c], m, 32));
#pragma unroll
        for (int c = 0; c < 32; ++c) h2[c] = fmaxf(h2[c], __shfl_xor(h2[c], m, 32));
#pragma unroll
        for (int c = 0; c < 32; ++c) h3[c] = fmaxf(h3[c], __shfl_xor(h3[c], m, 32));
    }

    // ---- store: out row = [h3, h2, h1, h0, x] ----
    float* orow = out + (size_t)q * 192;
    if (k == 0) {
        st32(orow, h3);
        st32(orow + 32, h2);
        st32(orow + 64, h1);
        st32(orow + 96, h0);
    }
    const float* xq = x + (size_t)q * DD;
    orow[128 + k] = xq[k];
    orow[160 + k] = xq[32 + k];
}

extern "C" void kernel_launch(void* const* d_in, const int* in_sizes, int n_in,
                              void* d_out, int out_size, void* d_ws, size_t ws_size,
                              hipStream_t stream) {
    const float* x   = (const float*)d_in[0];
    const float* pos = (const float*)d_in[1];
    const float* Wf  = (const float*)d_in[2];
    const float* bf  = (const float*)d_in[3];
    const float* W1  = (const float*)d_in[4];
    const float* b1  = (const float*)d_in[5];
    const float* W2  = (const float*)d_in[6];
    const float* b2  = (const float*)d_in[7];
    const float* Wl  = (const float*)d_in[8];
    const float* bl  = (const float*)d_in[9];
    float* out = (float*)d_out;

    char* ws = (char*)d_ws;
    int*   idx   = (int*)ws;                              // 1 MB
    float* bases = (float*)(ws + (1u << 20));             // 4 MB
    float* w0x   = (float*)(ws + 5u * (1u << 20));        // 8 KB
    float* w0k   = (float*)(ws + 5u * (1u << 20) + 8192); // 8 KB

    hipLaunchKernelGGL(prep_w_kernel, dim3(8), dim3(256), 0, stream, Wf, w0x, w0k);
    hipLaunchKernelGGL(ball_query_kernel, dim3(32), dim3(256), 0, stream, pos, idx);
    hipLaunchKernelGGL(bases_kernel, dim3(128), dim3(64), 0, stream,
                       x, w0x, W1, W2, Wl, bf, b1, b2, bl, bases);
    hipLaunchKernelGGL(mlp_kernel, dim3(1024), dim3(256), 0, stream,
                       x, idx, bases, w0k, W1, W2, Wl, out);
}

// Round 3
// 79.890 us; speedup vs baseline: 2.7632x; 2.7632x over previous
//
#include <hip/hip_runtime.h>
#include <hip/hip_bf16.h>

#define NB 4
#define NN 2048
#define KK 32
#define DD 64
#define R2C 0.64f

typedef __attribute__((ext_vector_type(8)))  short short8;   // 8 bf16 (4 VGPRs)
typedef __attribute__((ext_vector_type(16))) float f32x16;   // 32x32 MFMA acc

__device__ __forceinline__ unsigned short f2bf(float f) {
    __hip_bfloat16 h = __float2bfloat16(f);
    return reinterpret_cast<unsigned short&>(h);
}

// ---------------- prep: w0x for the bases kernel ----------------
// w0x[j][c] = Wf[j][c] - Wf[128+j][c]   (x coefficient of layer 0)
__global__ __launch_bounds__(256) void prep_w_kernel(const float* __restrict__ Wf,
                                                     float* __restrict__ w0x) {
    int t = blockIdx.x * 256 + threadIdx.x;
    if (t < 64 * 32) w0x[t] = Wf[t] - Wf[128 * 32 + t];
}

// ---------------- prep: x -> bf16 copy ----------------
__global__ __launch_bounds__(256) void prep_xbf_kernel(const float* __restrict__ x,
                                                       unsigned short* __restrict__ xbf) {
    int t = blockIdx.x * 256 + threadIdx.x;      // 131072 threads, 4 elems each
    float4 v = ((const float4*)x)[t];
    ushort4 o = make_ushort4(f2bf(v.x), f2bf(v.y), f2bf(v.z), f2bf(v.w));
    *(ushort4*)(xbf + 4 * (size_t)t) = o;
}

// ---------------- prep: weight B-fragments (bf16, MFMA layout) ----------------
// 16 frags x 64 lanes x 8 bf16. Frag slot (g=l>>5, j) carries B[k0 + 8g + j][l&31].
// f0-3:  w0k rows 16f..16f+15  (w0k = Wf[64:128]+Wf[128:192])
// f4-5:  W1 rows 0..31         f6-7: W2 rows 0..31     f8-9:  W2 rows 32..63
// f10-11: Wl rows 0..31        f12-13: Wl rows 32..63  f14-15: Wl rows 64..95
__global__ __launch_bounds__(256) void prep_wfrag_kernel(const float* __restrict__ Wf,
                                                         const float* __restrict__ W1,
                                                         const float* __restrict__ W2,
                                                         const float* __restrict__ Wl,
                                                         unsigned short* __restrict__ wfrag) {
    int t = blockIdx.x * 256 + threadIdx.x;      // 1024 total
    if (t >= 1024) return;
    int f = t >> 6, l = t & 63;
    int c = l & 31, g = l >> 5;
    unsigned short* dst = wfrag + (size_t)(f * 64 + l) * 8;
#pragma unroll
    for (int j = 0; j < 8; ++j) {
        int kl = 8 * g + j;
        float v;
        if (f < 4)       { int rr = 16 * f + kl;          v = Wf[(64 + rr) * 32 + c] + Wf[(128 + rr) * 32 + c]; }
        else if (f < 6)  { int rr = 16 * (f - 4) + kl;    v = W1[rr * 32 + c]; }
        else if (f < 8)  { int rr = 16 * (f - 6) + kl;    v = W2[rr * 32 + c]; }
        else if (f < 10) { int rr = 32 + 16 * (f - 8) + kl;  v = W2[rr * 32 + c]; }
        else if (f < 12) { int rr = 16 * (f - 10) + kl;      v = Wl[rr * 32 + c]; }
        else if (f < 14) { int rr = 32 + 16 * (f - 12) + kl; v = Wl[rr * 32 + c]; }
        else             { int rr = 64 + 16 * (f - 14) + kl; v = Wl[rr * 32 + c]; }
        dst[j] = f2bf(v);
    }
}

// ---------------- ball query (exact f32, matches reference op order) ----------------
__global__ __launch_bounds__(256) void ball_query_kernel(const float* __restrict__ pos,
                                                         int* __restrict__ idx) {
    __shared__ float sp[NN * 3];
    __shared__ float sq[NN];
    int bb = blockIdx.x >> 3;
    int nbase = (blockIdx.x & 7) * 256;
    const float* pb = pos + bb * NN * 3;
    for (int i = threadIdx.x; i < NN * 3; i += 256) sp[i] = pb[i];
    __syncthreads();
    for (int i = threadIdx.x; i < NN; i += 256) {
        float px = sp[i * 3], py = sp[i * 3 + 1], pz = sp[i * 3 + 2];
        sq[i] = __fadd_rn(__fadd_rn(__fmul_rn(px, px), __fmul_rn(py, py)), __fmul_rn(pz, pz));
    }
    __syncthreads();

    int n = nbase + threadIdx.x;
    float qx = sp[n * 3], qy = sp[n * 3 + 1], qz = sp[n * 3 + 2];
    float sqn = sq[n];
    int* op = idx + (bb * NN + n) * KK;
    int cnt = 0;
    for (int m = 0; m < NN; ++m) {
        float mx = sp[m * 3], my = sp[m * 3 + 1], mz = sp[m * 3 + 2];
        float dot = __fadd_rn(__fadd_rn(__fmul_rn(qx, mx), __fmul_rn(qy, my)), __fmul_rn(qz, mz));
        float d2 = __fsub_rn(__fadd_rn(sqn, sq[m]), __fmul_rn(2.0f, dot));
        if (d2 < R2C) {
            op[cnt++] = m;
            if (cnt == KK) break;
        }
    }
    int first = op[0];
    for (; cnt < KK; ++cnt) op[cnt] = first;
}

// ---------------- per-query bases (exact f32): base_L[c] = b_L[c] + x_q . W_L[x-part] ----------------
__global__ __launch_bounds__(64) void bases_kernel(const float* __restrict__ x,
                                                   const float* __restrict__ w0x,
                                                   const float* __restrict__ W1,
                                                   const float* __restrict__ W2,
                                                   const float* __restrict__ Wl,
                                                   const float* __restrict__ bf,
                                                   const float* __restrict__ b1,
                                                   const float* __restrict__ b2,
                                                   const float* __restrict__ bl,
                                                   float* __restrict__ bases) {
    int q = blockIdx.x * 64 + threadIdx.x;
    const float4* xr = (const float4*)(x + (size_t)q * DD);
    float a0[32], a1[32], a2[32], a3[32];
#pragma unroll
    for (int c = 0; c < 32; ++c) { a0[c] = bf[c]; a1[c] = b1[c]; a2[c] = b2[c]; a3[c] = bl[c]; }
    for (int j0 = 0; j0 < 16; ++j0) {
        float4 xv = xr[j0];
        float xs[4] = {xv.x, xv.y, xv.z, xv.w};
#pragma unroll
        for (int jj = 0; jj < 4; ++jj) {
            int j = j0 * 4 + jj;
            float v = xs[jj];
#pragma unroll
            for (int c = 0; c < 32; ++c) {
                a0[c] = fmaf(v, w0x[j * 32 + c], a0[c]);
                a1[c] = fmaf(v, W1[(32 + j) * 32 + c], a1[c]);
                a2[c] = fmaf(v, W2[(64 + j) * 32 + c], a2[c]);
                a3[c] = fmaf(v, Wl[(96 + j) * 32 + c], a3[c]);
            }
        }
    }
    float* bq = bases + (size_t)q * 128;
    float4* b4 = (float4*)bq;
#pragma unroll
    for (int c = 0; c < 8; ++c) b4[c]      = make_float4(a0[4*c], a0[4*c+1], a0[4*c+2], a0[4*c+3]);
#pragma unroll
    for (int c = 0; c < 8; ++c) b4[8 + c]  = make_float4(a1[4*c], a1[4*c+1], a1[4*c+2], a1[4*c+3]);
#pragma unroll
    for (int c = 0; c < 8; ++c) b4[16 + c] = make_float4(a2[4*c], a2[4*c+1], a2[4*c+2], a2[4*c+3]);
#pragma unroll
    for (int c = 0; c < 8; ++c) b4[24 + c] = make_float4(a3[4*c], a3[4*c+1], a3[4*c+2], a3[4*c+3]);
}

// ---------------- main: one wave per query, MFMA MLP + row-max ----------------
// D/C layout (verified): col = lane&31, row = (reg&3) + 8*(reg>>2) + 4*(lane>>5).
// A-frag: lane supplies row (lane&31), slots j -> k-label 8*(lane>>5)+j (+16*step).
// Row-label errors cancel (max is row-blind; LDS round-trips self-consistent).
#define HSTRIDE 40   // ushorts per h-row in LDS (80B, 16B-aligned, conflict-light)

__device__ __forceinline__ void post_layer(const f32x16& acc, float bs,
                                           unsigned short* hl, int col, int g,
                                           float& mx, short8& f0, short8& f1) {
    float v[16];
#pragma unroll
    for (int p = 0; p < 16; ++p) v[p] = fmaxf(acc[p] + bs, 0.0f);   // bias/base + relu
    float m = v[0];
#pragma unroll
    for (int p = 1; p < 16; ++p) m = fmaxf(m, v[p]);
    m = fmaxf(m, __shfl_xor(m, 32));     // combine wave halves (rows r vs r+4)
    mx = m;
    // write relu'd bf16 rows to LDS [32][HSTRIDE]
#pragma unroll
    for (int p = 0; p < 16; ++p) {
        int r = (p & 3) + 8 * (p >> 2) + 4 * g;
        hl[r * HSTRIDE + col] = f2bf(v[p]);
    }
    // read back as A-fragments for the next layers (row = lane&31)
    const unsigned short* row = hl + col * HSTRIDE;
    f0 = *(const short8*)(row + 8 * g);        // k-labels 0..15
    f1 = *(const short8*)(row + 16 + 8 * g);   // k-labels 16..31
}

__global__ __launch_bounds__(256) void mfma_kernel(const float* __restrict__ x,
                                                   const int* __restrict__ idx,
                                                   const float* __restrict__ bases,
                                                   const unsigned short* __restrict__ xbf,
                                                   const unsigned short* __restrict__ wfrag,
                                                   float* __restrict__ out) {
    __shared__ unsigned short hlds[4][32 * HSTRIDE];
    int wid = threadIdx.x >> 6, lane = threadIdx.x & 63;
    int q = blockIdx.x * 4 + wid;                 // one query per wave
    int col = lane & 31, g = lane >> 5;
    unsigned short* hl = hlds[wid];

    // weight B-fragments: register-resident for the whole wave (64 VGPRs)
    short8 wf[16];
    const short8* wfp = (const short8*)wfrag;
#pragma unroll
    for (int f = 0; f < 16; ++f) wf[f] = wfp[f * 64 + lane];

    // neighbor gather: lane's A-row = col; 8 contiguous bf16 per frag
    int nb = (q >> 11) * NN + idx[q * KK + col];
    const short8* xrow = (const short8*)(xbf + (size_t)nb * DD + g * 8);
    short8 xk0 = xrow[0], xk1 = xrow[2], xk2 = xrow[4], xk3 = xrow[6];

    const float* bq = bases + (size_t)q * 128;
    float bs0 = bq[col], bs1 = bq[32 + col], bs2 = bq[64 + col], bs3 = bq[96 + col];

    // ---- L0: XK[32x64] @ w0k[64x32] ----
    f32x16 acc;
#pragma unroll
    for (int p = 0; p < 16; ++p) acc[p] = 0.0f;
    acc = __builtin_amdgcn_mfma_f32_32x32x16_bf16(xk0, wf[0], acc, 0, 0, 0);
    acc = __builtin_amdgcn_mfma_f32_32x32x16_bf16(xk1, wf[1], acc, 0, 0, 0);
    acc = __builtin_amdgcn_mfma_f32_32x32x16_bf16(xk2, wf[2], acc, 0, 0, 0);
    acc = __builtin_amdgcn_mfma_f32_32x32x16_bf16(xk3, wf[3], acc, 0, 0, 0);
    float mx0; short8 h0f0, h0f1;
    post_layer(acc, bs0, hl, col, g, mx0, h0f0, h0f1);

    // ---- L1: H0[32x32] @ W1a ----
#pragma unroll
    for (int p = 0; p < 16; ++p) acc[p] = 0.0f;
    acc = __builtin_amdgcn_mfma_f32_32x32x16_bf16(h0f0, wf[4], acc, 0, 0, 0);
    acc = __builtin_amdgcn_mfma_f32_32x32x16_bf16(h0f1, wf[5], acc, 0, 0, 0);
    float mx1; short8 h1f0, h1f1;
    post_layer(acc, bs1, hl, col, g, mx1, h1f0, h1f1);

    // ---- L2: H1 @ W2a + H0 @ W2b ----
#pragma unroll
    for (int p = 0; p < 16; ++p) acc[p] = 0.0f;
    acc = __builtin_amdgcn_mfma_f32_32x32x16_bf16(h1f0, wf[6], acc, 0, 0, 0);
    acc = __builtin_amdgcn_mfma_f32_32x32x16_bf16(h1f1, wf[7], acc, 0, 0, 0);
    acc = __builtin_amdgcn_mfma_f32_32x32x16_bf16(h0f0, wf[8], acc, 0, 0, 0);
    acc = __builtin_amdgcn_mfma_f32_32x32x16_bf16(h0f1, wf[9], acc, 0, 0, 0);
    float mx2; short8 h2f0, h2f1;
    post_layer(acc, bs2, hl, col, g, mx2, h2f0, h2f1);

    // ---- L3: H2 @ Wla + H1 @ Wlb + H0 @ Wlc (no relu) ----
#pragma unroll
    for (int p = 0; p < 16; ++p) acc[p] = 0.0f;
    acc = __builtin_amdgcn_mfma_f32_32x32x16_bf16(h2f0, wf[10], acc, 0, 0, 0);
    acc = __builtin_amdgcn_mfma_f32_32x32x16_bf16(h2f1, wf[11], acc, 0, 0, 0);
    acc = __builtin_amdgcn_mfma_f32_32x32x16_bf16(h1f0, wf[12], acc, 0, 0, 0);
    acc = __builtin_amdgcn_mfma_f32_32x32x16_bf16(h1f1, wf[13], acc, 0, 0, 0);
    acc = __builtin_amdgcn_mfma_f32_32x32x16_bf16(h0f0, wf[14], acc, 0, 0, 0);
    acc = __builtin_amdgcn_mfma_f32_32x32x16_bf16(h0f1, wf[15], acc, 0, 0, 0);
    float m3 = acc[0] + bs3;
#pragma unroll
    for (int p = 1; p < 16; ++p) m3 = fmaxf(m3, acc[p] + bs3);
    m3 = fmaxf(m3, __shfl_xor(m3, 32));

    // ---- store: out row = [h3, h2, h1, h0, x] ----
    float* orow = out + (size_t)q * 192;
    if (g == 0) {
        orow[col]      = m3;
        orow[32 + col] = mx2;
        orow[64 + col] = mx1;
        orow[96 + col] = mx0;
    }
    orow[128 + lane] = x[(size_t)q * DD + lane];
}

extern "C" void kernel_launch(void* const* d_in, const int* in_sizes, int n_in,
                              void* d_out, int out_size, void* d_ws, size_t ws_size,
                              hipStream_t stream) {
    const float* x   = (const float*)d_in[0];
    const float* pos = (const float*)d_in[1];
    const float* Wf  = (const float*)d_in[2];
    const float* bf  = (const float*)d_in[3];
    const float* W1  = (const float*)d_in[4];
    const float* b1  = (const float*)d_in[5];
    const float* W2  = (const float*)d_in[6];
    const float* b2  = (const float*)d_in[7];
    const float* Wl  = (const float*)d_in[8];
    const float* bl  = (const float*)d_in[9];
    float* out = (float*)d_out;

    char* ws = (char*)d_ws;
    int*            idx   = (int*)ws;                                    // 1 MB
    float*          bases = (float*)(ws + (1u << 20));                   // 4 MB
    float*          w0x   = (float*)(ws + 5u * (1u << 20));              // 8 KB
    unsigned short* wfrag = (unsigned short*)(ws + 5u * (1u << 20) + 8192);        // 16 KB
    unsigned short* xbf   = (unsigned short*)(ws + 5u * (1u << 20) + 8192 + 16384); // 1 MB

    hipLaunchKernelGGL(prep_w_kernel, dim3(8), dim3(256), 0, stream, Wf, w0x);
    hipLaunchKernelGGL(prep_wfrag_kernel, dim3(4), dim3(256), 0, stream, Wf, W1, W2, Wl, wfrag);
    hipLaunchKernelGGL(prep_xbf_kernel, dim3(512), dim3(256), 0, stream, x, xbf);
    hipLaunchKernelGGL(ball_query_kernel, dim3(32), dim3(256), 0, stream, pos, idx);
    hipLaunchKernelGGL(bases_kernel, dim3(128), dim3(64), 0, stream,
                       x, w0x, W1, W2, Wl, bf, b1, b2, bl, bases);
    hipLaunchKernelGGL(mfma_kernel, dim3(2048), dim3(256), 0, stream,
                       x, idx, bases, xbf, wfrag, out);
}

// Round 4
// 70.630 us; speedup vs baseline: 3.1255x; 1.1311x over previous
//
#include <hip/hip_runtime.h>
#include <hip/hip_bf16.h>

#define NB 4
#define NN 2048
#define KK 32
#define DD 64
#define R2C 0.64f

typedef __attribute__((ext_vector_type(8)))  short short8;   // 8 bf16 (4 VGPRs)
typedef __attribute__((ext_vector_type(16))) float f32x16;   // 32x32 MFMA acc

__device__ __forceinline__ unsigned short f2bf(float f) {
    __hip_bfloat16 h = __float2bfloat16(f);
    return reinterpret_cast<unsigned short&>(h);
}

// ---------------- prep: transposed x-part weights wxt[128][64] + packed biases ball[128] ----------------
// ch = L*32+c: L0: Wf[j][c]-Wf[128+j][c]; L1: W1[32+j][c]; L2: W2[64+j][c]; L3: Wl[96+j][c]
__global__ __launch_bounds__(256) void prep_wx_kernel(const float* __restrict__ Wf,
                                                      const float* __restrict__ W1,
                                                      const float* __restrict__ W2,
                                                      const float* __restrict__ Wl,
                                                      const float* __restrict__ bf,
                                                      const float* __restrict__ b1,
                                                      const float* __restrict__ b2,
                                                      const float* __restrict__ bl,
                                                      float* __restrict__ wxt,
                                                      float* __restrict__ ball) {
    int t = blockIdx.x * 256 + threadIdx.x;          // 8192 = 128 ch x 64 j
    int ch = t >> 6, j = t & 63;
    int L = ch >> 5, c = ch & 31;
    float v;
    if (L == 0)      v = Wf[j * 32 + c] - Wf[(128 + j) * 32 + c];
    else if (L == 1) v = W1[(32 + j) * 32 + c];
    else if (L == 2) v = W2[(64 + j) * 32 + c];
    else             v = Wl[(96 + j) * 32 + c];
    wxt[ch * 64 + j] = v;
    if (j == 0) ball[ch] = (L == 0 ? bf[c] : L == 1 ? b1[c] : L == 2 ? b2[c] : bl[c]);
}

// ---------------- prep: x -> bf16 copy ----------------
__global__ __launch_bounds__(256) void prep_xbf_kernel(const float* __restrict__ x,
                                                       unsigned short* __restrict__ xbf) {
    int t = blockIdx.x * 256 + threadIdx.x;      // 131072 threads, 4 elems each
    float4 v = ((const float4*)x)[t];
    ushort4 o = make_ushort4(f2bf(v.x), f2bf(v.y), f2bf(v.z), f2bf(v.w));
    *(ushort4*)(xbf + 4 * (size_t)t) = o;
}

// ---------------- prep: weight B-fragments (bf16, MFMA layout) ----------------
// 16 frags x 64 lanes x 8 bf16. Frag slot (g=l>>5, j) carries B[k0 + 8g + j][l&31].
__global__ __launch_bounds__(256) void prep_wfrag_kernel(const float* __restrict__ Wf,
                                                         const float* __restrict__ W1,
                                                         const float* __restrict__ W2,
                                                         const float* __restrict__ Wl,
                                                         unsigned short* __restrict__ wfrag) {
    int t = blockIdx.x * 256 + threadIdx.x;      // 1024 total
    if (t >= 1024) return;
    int f = t >> 6, l = t & 63;
    int c = l & 31, g = l >> 5;
    unsigned short* dst = wfrag + (size_t)(f * 64 + l) * 8;
#pragma unroll
    for (int j = 0; j < 8; ++j) {
        int kl = 8 * g + j;
        float v;
        if (f < 4)       { int rr = 16 * f + kl;          v = Wf[(64 + rr) * 32 + c] + Wf[(128 + rr) * 32 + c]; }
        else if (f < 6)  { int rr = 16 * (f - 4) + kl;    v = W1[rr * 32 + c]; }
        else if (f < 8)  { int rr = 16 * (f - 6) + kl;    v = W2[rr * 32 + c]; }
        else if (f < 10) { int rr = 32 + 16 * (f - 8) + kl;  v = W2[rr * 32 + c]; }
        else if (f < 12) { int rr = 16 * (f - 10) + kl;      v = Wl[rr * 32 + c]; }
        else if (f < 14) { int rr = 32 + 16 * (f - 12) + kl; v = Wl[rr * 32 + c]; }
        else             { int rr = 64 + 16 * (f - 14) + kl; v = Wl[rr * 32 + c]; }
        dst[j] = f2bf(v);
    }
}

// ---------------- ball query (exact f32, matches reference op order) ----------------
__global__ __launch_bounds__(256) void ball_query_kernel(const float* __restrict__ pos,
                                                         int* __restrict__ idx) {
    __shared__ float sp[NN * 3];
    __shared__ float sq[NN];
    int bb = blockIdx.x >> 3;
    int nbase = (blockIdx.x & 7) * 256;
    const float* pb = pos + bb * NN * 3;
    for (int i = threadIdx.x; i < NN * 3; i += 256) sp[i] = pb[i];
    __syncthreads();
    for (int i = threadIdx.x; i < NN; i += 256) {
        float px = sp[i * 3], py = sp[i * 3 + 1], pz = sp[i * 3 + 2];
        sq[i] = __fadd_rn(__fadd_rn(__fmul_rn(px, px), __fmul_rn(py, py)), __fmul_rn(pz, pz));
    }
    __syncthreads();

    int n = nbase + threadIdx.x;
    float qx = sp[n * 3], qy = sp[n * 3 + 1], qz = sp[n * 3 + 2];
    float sqn = sq[n];
    int* op = idx + (bb * NN + n) * KK;
    int cnt = 0;
    for (int m = 0; m < NN; ++m) {
        float mx = sp[m * 3], my = sp[m * 3 + 1], mz = sp[m * 3 + 2];
        float dot = __fadd_rn(__fadd_rn(__fmul_rn(qx, mx), __fmul_rn(qy, my)), __fmul_rn(qz, mz));
        float d2 = __fsub_rn(__fadd_rn(sqn, sq[m]), __fmul_rn(2.0f, dot));
        if (d2 < R2C) {
            op[cnt++] = m;
            if (cnt == KK) break;
        }
    }
    int first = op[0];
    for (; cnt < KK; ++cnt) op[cnt] = first;
}

// ---------------- main: one wave per query, fused bases + MFMA MLP + row-max ----------------
// D/C layout (verified): col = lane&31, row = (reg&3) + 8*(reg>>2) + 4*(lane>>5).
#define HSTRIDE 40   // ushorts per h-row in LDS (80B, 16B-aligned)

__device__ __forceinline__ void post_layer(const f32x16& acc, float bs,
                                           unsigned short* hl, int col, int g,
                                           float& mx, short8& f0, short8& f1) {
    float v[16];
#pragma unroll
    for (int p = 0; p < 16; ++p) v[p] = fmaxf(acc[p] + bs, 0.0f);   // base + relu
    float m = v[0];
#pragma unroll
    for (int p = 1; p < 16; ++p) m = fmaxf(m, v[p]);
    m = fmaxf(m, __shfl_xor(m, 32));     // combine wave halves
    mx = m;
#pragma unroll
    for (int p = 0; p < 16; ++p) {
        int r = (p & 3) + 8 * (p >> 2) + 4 * g;
        hl[r * HSTRIDE + col] = f2bf(v[p]);
    }
    const unsigned short* row = hl + col * HSTRIDE;
    f0 = *(const short8*)(row + 8 * g);
    f1 = *(const short8*)(row + 16 + 8 * g);
}

__global__ __launch_bounds__(256) void mfma_kernel(const float* __restrict__ x,
                                                   const int* __restrict__ idx,
                                                   const unsigned short* __restrict__ xbf,
                                                   const unsigned short* __restrict__ wfrag,
                                                   const float* __restrict__ wxt,
                                                   const float* __restrict__ ball,
                                                   float* __restrict__ out) {
    __shared__ unsigned short hlds[4][32 * HSTRIDE];
    int wid = threadIdx.x >> 6, lane = threadIdx.x & 63;
    int q = blockIdx.x * 4 + wid;                 // one query per wave
    int qs = __builtin_amdgcn_readfirstlane(q);   // force wave-uniform (SGPR path)
    int col = lane & 31, g = lane >> 5;
    unsigned short* hl = hlds[wid];

    // weight B-fragments: register-resident (64 VGPRs)
    short8 wf[16];
    const short8* wfp = (const short8*)wfrag;
#pragma unroll
    for (int f = 0; f < 16; ++f) wf[f] = wfp[f * 64 + lane];

    // neighbor gather: lane's A-row = col
    int nb = (qs >> 11) * NN + idx[qs * KK + col];
    const short8* xrow = (const short8*)(xbf + (size_t)nb * DD + g * 8);
    short8 xk0 = xrow[0], xk1 = xrow[2], xk2 = xrow[4], xk3 = xrow[6];

    // ---- fused bases: lane computes channels (lane) and (64+lane); x row via SGPR broadcast ----
    // identical ascending-j fmaf chain as the old f32 bases kernel (bit-identical numerics)
    const float* xq = x + (size_t)qs * DD;
    float accA = ball[lane];
    float accB = ball[64 + lane];
    const float4* wA = (const float4*)(wxt + (size_t)lane * DD);
    const float4* wB = (const float4*)(wxt + (size_t)(64 + lane) * DD);
#pragma unroll
    for (int j0 = 0; j0 < 16; ++j0) {
        float4 a4 = wA[j0], b4 = wB[j0];
        float x0 = xq[4 * j0], x1 = xq[4 * j0 + 1], x2 = xq[4 * j0 + 2], x3 = xq[4 * j0 + 3];
        accA = fmaf(x0, a4.x, accA); accA = fmaf(x1, a4.y, accA);
        accA = fmaf(x2, a4.z, accA); accA = fmaf(x3, a4.w, accA);
        accB = fmaf(x0, b4.x, accB); accB = fmaf(x1, b4.y, accB);
        accB = fmaf(x2, b4.z, accB); accB = fmaf(x3, b4.w, accB);
    }
    // redistribute: bs0..bs3 for this lane's output column
    float bs0 = __shfl(accA, col, 64);
    float bs1 = __shfl(accA, 32 + col, 64);
    float bs2 = __shfl(accB, col, 64);
    float bs3 = __shfl(accB, 32 + col, 64);

    // ---- L0: XK[32x64] @ w0k[64x32] ----
    f32x16 acc;
#pragma unroll
    for (int p = 0; p < 16; ++p) acc[p] = 0.0f;
    acc = __builtin_amdgcn_mfma_f32_32x32x16_bf16(xk0, wf[0], acc, 0, 0, 0);
    acc = __builtin_amdgcn_mfma_f32_32x32x16_bf16(xk1, wf[1], acc, 0, 0, 0);
    acc = __builtin_amdgcn_mfma_f32_32x32x16_bf16(xk2, wf[2], acc, 0, 0, 0);
    acc = __builtin_amdgcn_mfma_f32_32x32x16_bf16(xk3, wf[3], acc, 0, 0, 0);
    float mx0; short8 h0f0, h0f1;
    post_layer(acc, bs0, hl, col, g, mx0, h0f0, h0f1);

    // ---- L1 ----
#pragma unroll
    for (int p = 0; p < 16; ++p) acc[p] = 0.0f;
    acc = __builtin_amdgcn_mfma_f32_32x32x16_bf16(h0f0, wf[4], acc, 0, 0, 0);
    acc = __builtin_amdgcn_mfma_f32_32x32x16_bf16(h0f1, wf[5], acc, 0, 0, 0);
    float mx1; short8 h1f0, h1f1;
    post_layer(acc, bs1, hl, col, g, mx1, h1f0, h1f1);

    // ---- L2 ----
#pragma unroll
    for (int p = 0; p < 16; ++p) acc[p] = 0.0f;
    acc = __builtin_amdgcn_mfma_f32_32x32x16_bf16(h1f0, wf[6], acc, 0, 0, 0);
    acc = __builtin_amdgcn_mfma_f32_32x32x16_bf16(h1f1, wf[7], acc, 0, 0, 0);
    acc = __builtin_amdgcn_mfma_f32_32x32x16_bf16(h0f0, wf[8], acc, 0, 0, 0);
    acc = __builtin_amdgcn_mfma_f32_32x32x16_bf16(h0f1, wf[9], acc, 0, 0, 0);
    float mx2; short8 h2f0, h2f1;
    post_layer(acc, bs2, hl, col, g, mx2, h2f0, h2f1);

    // ---- L3 (no relu) ----
#pragma unroll
    for (int p = 0; p < 16; ++p) acc[p] = 0.0f;
    acc = __builtin_amdgcn_mfma_f32_32x32x16_bf16(h2f0, wf[10], acc, 0, 0, 0);
    acc = __builtin_amdgcn_mfma_f32_32x32x16_bf16(h2f1, wf[11], acc, 0, 0, 0);
    acc = __builtin_amdgcn_mfma_f32_32x32x16_bf16(h1f0, wf[12], acc, 0, 0, 0);
    acc = __builtin_amdgcn_mfma_f32_32x32x16_bf16(h1f1, wf[13], acc, 0, 0, 0);
    acc = __builtin_amdgcn_mfma_f32_32x32x16_bf16(h0f0, wf[14], acc, 0, 0, 0);
    acc = __builtin_amdgcn_mfma_f32_32x32x16_bf16(h0f1, wf[15], acc, 0, 0, 0);
    float m3 = acc[0] + bs3;
#pragma unroll
    for (int p = 1; p < 16; ++p) m3 = fmaxf(m3, acc[p] + bs3);
    m3 = fmaxf(m3, __shfl_xor(m3, 32));

    // ---- store: out row = [h3, h2, h1, h0, x] ----
    float* orow = out + (size_t)qs * 192;
    if (g == 0) {
        orow[col]      = m3;
        orow[32 + col] = mx2;
        orow[64 + col] = mx1;
        orow[96 + col] = mx0;
    }
    orow[128 + lane] = xq[lane];
}

extern "C" void kernel_launch(void* const* d_in, const int* in_sizes, int n_in,
                              void* d_out, int out_size, void* d_ws, size_t ws_size,
                              hipStream_t stream) {
    const float* x   = (const float*)d_in[0];
    const float* pos = (const float*)d_in[1];
    const float* Wf  = (const float*)d_in[2];
    const float* bf  = (const float*)d_in[3];
    const float* W1  = (const float*)d_in[4];
    const float* b1  = (const float*)d_in[5];
    const float* W2  = (const float*)d_in[6];
    const float* b2  = (const float*)d_in[7];
    const float* Wl  = (const float*)d_in[8];
    const float* bl  = (const float*)d_in[9];
    float* out = (float*)d_out;

    char* ws = (char*)d_ws;
    int*            idx   = (int*)ws;                                     // 1 MB
    float*          wxt   = (float*)(ws + (1u << 20));                    // 32 KB
    float*          ballp = (float*)(ws + (1u << 20) + 32768);            // 512 B
    unsigned short* wfrag = (unsigned short*)(ws + (1u << 20) + 40960);   // 16 KB
    unsigned short* xbf   = (unsigned short*)(ws + 2u * (1u << 20));      // 1 MB

    hipLaunchKernelGGL(prep_wx_kernel, dim3(32), dim3(256), 0, stream,
                       Wf, W1, W2, Wl, bf, b1, b2, bl, wxt, ballp);
    hipLaunchKernelGGL(prep_wfrag_kernel, dim3(4), dim3(256), 0, stream, Wf, W1, W2, Wl, wfrag);
    hipLaunchKernelGGL(prep_xbf_kernel, dim3(512), dim3(256), 0, stream, x, xbf);
    hipLaunchKernelGGL(ball_query_kernel, dim3(32), dim3(256), 0, stream, pos, idx);
    hipLaunchKernelGGL(mfma_kernel, dim3(2048), dim3(256), 0, stream,
                       x, idx, xbf, wfrag, wxt, ballp, out);
}

// Round 5
// 49.246 us; speedup vs baseline: 4.4828x; 1.4342x over previous
//
#include <hip/hip_runtime.h>
#include <hip/hip_bf16.h>

#define NB 4
#define NN 2048
#define KK 32
#define DD 64
#define R2C 0.64f

typedef __attribute__((ext_vector_type(8)))  short short8;   // 8 bf16 (4 VGPRs)
typedef __attribute__((ext_vector_type(16))) float f32x16;   // 32x32 MFMA acc

__device__ __forceinline__ unsigned short f2bf(float f) {
    __hip_bfloat16 h = __float2bfloat16(f);
    return reinterpret_cast<unsigned short&>(h);
}

// ---------------- single prep kernel: xbf | wxt+ball | wfrag ----------------
// blocks [0,512): x->bf16; [512,544): wxt[128][64]+ball[128]; [544,548): wfrag
__global__ __launch_bounds__(256) void prep_all_kernel(const float* __restrict__ x,
                                                       const float* __restrict__ Wf,
                                                       const float* __restrict__ W1,
                                                       const float* __restrict__ W2,
                                                       const float* __restrict__ Wl,
                                                       const float* __restrict__ bf,
                                                       const float* __restrict__ b1,
                                                       const float* __restrict__ b2,
                                                       const float* __restrict__ bl,
                                                       unsigned short* __restrict__ xbf,
                                                       float* __restrict__ wxt,
                                                       float* __restrict__ ball,
                                                       unsigned short* __restrict__ wfrag) {
    int blk = blockIdx.x;
    if (blk < 512) {
        int t = blk * 256 + threadIdx.x;          // 131072 threads x 4 elems
        float4 v = ((const float4*)x)[t];
        ushort4 o = make_ushort4(f2bf(v.x), f2bf(v.y), f2bf(v.z), f2bf(v.w));
        *(ushort4*)(xbf + 4 * (size_t)t) = o;
    } else if (blk < 544) {
        int t = (blk - 512) * 256 + threadIdx.x;  // 8192 = 128 ch x 64 j
        int ch = t >> 6, j = t & 63;
        int L = ch >> 5, c = ch & 31;
        float v;
        if (L == 0)      v = Wf[j * 32 + c] - Wf[(128 + j) * 32 + c];
        else if (L == 1) v = W1[(32 + j) * 32 + c];
        else if (L == 2) v = W2[(64 + j) * 32 + c];
        else             v = Wl[(96 + j) * 32 + c];
        wxt[ch * 64 + j] = v;
        if (j == 0) ball[ch] = (L == 0 ? bf[c] : L == 1 ? b1[c] : L == 2 ? b2[c] : bl[c]);
    } else {
        int t = (blk - 544) * 256 + threadIdx.x;  // 1024
        int f = t >> 6, l = t & 63;
        int c = l & 31, g = l >> 5;
        unsigned short* dst = wfrag + (size_t)(f * 64 + l) * 8;
#pragma unroll
        for (int j = 0; j < 8; ++j) {
            int kl = 8 * g + j;
            float v;
            if (f < 4)       { int rr = 16 * f + kl;             v = Wf[(64 + rr) * 32 + c] + Wf[(128 + rr) * 32 + c]; }
            else if (f < 6)  { int rr = 16 * (f - 4) + kl;       v = W1[rr * 32 + c]; }
            else if (f < 8)  { int rr = 16 * (f - 6) + kl;       v = W2[rr * 32 + c]; }
            else if (f < 10) { int rr = 32 + 16 * (f - 8) + kl;  v = W2[rr * 32 + c]; }
            else if (f < 12) { int rr = 16 * (f - 10) + kl;      v = Wl[rr * 32 + c]; }
            else if (f < 14) { int rr = 32 + 16 * (f - 12) + kl; v = Wl[rr * 32 + c]; }
            else             { int rr = 64 + 16 * (f - 14) + kl; v = Wl[rr * 32 + c]; }
            dst[j] = f2bf(v);
        }
    }
}

// ---------------- fused main: ball query + bases + MFMA MLP + row-max ----------------
// D/C layout (verified): col = lane&31, row = (reg&3) + 8*(reg>>2) + 4*(lane>>5).
#define HSTRIDE 40   // ushorts per h-row in LDS (80B, 16B-aligned)

__device__ __forceinline__ void post_layer(const f32x16& acc, float bs,
                                           unsigned short* hl, int col, int g,
                                           float& mx, short8& f0, short8& f1) {
    float v[16];
#pragma unroll
    for (int p = 0; p < 16; ++p) v[p] = fmaxf(acc[p] + bs, 0.0f);   // base + relu
    float m = v[0];
#pragma unroll
    for (int p = 1; p < 16; ++p) m = fmaxf(m, v[p]);
    m = fmaxf(m, __shfl_xor(m, 32));     // combine wave halves
    mx = m;
#pragma unroll
    for (int p = 0; p < 16; ++p) {
        int r = (p & 3) + 8 * (p >> 2) + 4 * g;
        hl[r * HSTRIDE + col] = f2bf(v[p]);
    }
    const unsigned short* row = hl + col * HSTRIDE;
    f0 = *(const short8*)(row + 8 * g);
    f1 = *(const short8*)(row + 16 + 8 * g);
}

__global__ __launch_bounds__(256) void fused_kernel(const float* __restrict__ x,
                                                    const float* __restrict__ pos,
                                                    const unsigned short* __restrict__ xbf,
                                                    const unsigned short* __restrict__ wfrag,
                                                    const float* __restrict__ wxt,
                                                    const float* __restrict__ ball,
                                                    float* __restrict__ out) {
    __shared__ unsigned short hlds[4][32 * HSTRIDE];
    __shared__ int nbrs[4][KK];
    int wid = threadIdx.x >> 6, lane = threadIdx.x & 63;
    int qs = __builtin_amdgcn_readfirstlane(blockIdx.x * 4 + wid);  // one query per wave
    int col = lane & 31, g = lane >> 5;
    int b = qs >> 11, n = qs & (NN - 1);
    unsigned short* hl = hlds[wid];
    int* nbr = nbrs[wid];

    // weight B-fragments: register/AGPR-resident for the whole wave
    short8 wf[16];
    const short8* wfp = (const short8*)wfrag;
#pragma unroll
    for (int f = 0; f < 16; ++f) wf[f] = wfp[f * 64 + lane];

    // ---- fused bases: lane computes channels (lane) and (64+lane); x row wave-uniform ----
    const float* xq = x + (size_t)qs * DD;
    float accA = ball[lane];
    float accB = ball[64 + lane];
    const float4* wA = (const float4*)(wxt + (size_t)lane * DD);
    const float4* wB = (const float4*)(wxt + (size_t)(64 + lane) * DD);
#pragma unroll
    for (int j0 = 0; j0 < 16; ++j0) {
        float4 a4 = wA[j0], b4 = wB[j0];
        float x0 = xq[4 * j0], x1 = xq[4 * j0 + 1], x2 = xq[4 * j0 + 2], x3 = xq[4 * j0 + 3];
        accA = fmaf(x0, a4.x, accA); accA = fmaf(x1, a4.y, accA);
        accA = fmaf(x2, a4.z, accA); accA = fmaf(x3, a4.w, accA);
        accB = fmaf(x0, b4.x, accB); accB = fmaf(x1, b4.y, accB);
        accB = fmaf(x2, b4.z, accB); accB = fmaf(x3, b4.w, accB);
    }
    float bs0 = __shfl(accA, col, 64);
    float bs1 = __shfl(accA, 32 + col, 64);
    float bs2 = __shfl(accB, col, 64);
    float bs3 = __shfl(accB, 32 + col, 64);

    // ---- in-wave ball query: chunked scan, 64 candidates per iteration ----
    // d2 arithmetic identical to reference: (sq[n]+sq[m]) - 2*dot, no contraction.
    const float* pb = pos + (size_t)b * NN * 3;
    float qx = pb[3 * n], qy = pb[3 * n + 1], qz = pb[3 * n + 2];
    float sqn = __fadd_rn(__fadd_rn(__fmul_rn(qx, qx), __fmul_rn(qy, qy)), __fmul_rn(qz, qz));
    int cnt = 0;
    for (int m0 = 0; m0 < NN && cnt < KK; m0 += 64) {
        int m = m0 + lane;
        float mx3 = pb[3 * m], my3 = pb[3 * m + 1], mz3 = pb[3 * m + 2];
        float sqm = __fadd_rn(__fadd_rn(__fmul_rn(mx3, mx3), __fmul_rn(my3, my3)), __fmul_rn(mz3, mz3));
        float dot = __fadd_rn(__fadd_rn(__fmul_rn(qx, mx3), __fmul_rn(qy, my3)), __fmul_rn(qz, mz3));
        float d2 = __fsub_rn(__fadd_rn(sqn, sqm), __fmul_rn(2.0f, dot));
        bool hit = d2 < R2C;
        unsigned long long mask = __ballot(hit);
        if (hit) {
            int p = cnt + (int)__popcll(mask & ((1ULL << lane) - 1ULL));
            if (p < KK) nbr[p] = m;
        }
        cnt = __builtin_amdgcn_readfirstlane(cnt + (int)__popcll(mask));
    }
    int nbn = nbr[col < cnt ? col : 0];      // pad with first hit

    // neighbor gather: lane's A-row = col
    const short8* xrow = (const short8*)(xbf + (size_t)(b * NN + nbn) * DD + g * 8);
    short8 xk0 = xrow[0], xk1 = xrow[2], xk2 = xrow[4], xk3 = xrow[6];

    // ---- L0: XK[32x64] @ w0k[64x32], two independent 2-chains ----
    f32x16 acc, acc2;
#pragma unroll
    for (int p = 0; p < 16; ++p) { acc[p] = 0.0f; acc2[p] = 0.0f; }
    acc  = __builtin_amdgcn_mfma_f32_32x32x16_bf16(xk0, wf[0], acc, 0, 0, 0);
    acc2 = __builtin_amdgcn_mfma_f32_32x32x16_bf16(xk2, wf[2], acc2, 0, 0, 0);
    acc  = __builtin_amdgcn_mfma_f32_32x32x16_bf16(xk1, wf[1], acc, 0, 0, 0);
    acc2 = __builtin_amdgcn_mfma_f32_32x32x16_bf16(xk3, wf[3], acc2, 0, 0, 0);
#pragma unroll
    for (int p = 0; p < 16; ++p) acc[p] += acc2[p];
    float mx0; short8 h0f0, h0f1;
    post_layer(acc, bs0, hl, col, g, mx0, h0f0, h0f1);

    // ---- L1 ----
#pragma unroll
    for (int p = 0; p < 16; ++p) acc[p] = 0.0f;
    acc = __builtin_amdgcn_mfma_f32_32x32x16_bf16(h0f0, wf[4], acc, 0, 0, 0);
    acc = __builtin_amdgcn_mfma_f32_32x32x16_bf16(h0f1, wf[5], acc, 0, 0, 0);
    float mx1; short8 h1f0, h1f1;
    post_layer(acc, bs1, hl, col, g, mx1, h1f0, h1f1);

    // ---- L2: two independent 2-chains ----
#pragma unroll
    for (int p = 0; p < 16; ++p) { acc[p] = 0.0f; acc2[p] = 0.0f; }
    acc  = __builtin_amdgcn_mfma_f32_32x32x16_bf16(h1f0, wf[6], acc, 0, 0, 0);
    acc2 = __builtin_amdgcn_mfma_f32_32x32x16_bf16(h0f0, wf[8], acc2, 0, 0, 0);
    acc  = __builtin_amdgcn_mfma_f32_32x32x16_bf16(h1f1, wf[7], acc, 0, 0, 0);
    acc2 = __builtin_amdgcn_mfma_f32_32x32x16_bf16(h0f1, wf[9], acc2, 0, 0, 0);
#pragma unroll
    for (int p = 0; p < 16; ++p) acc[p] += acc2[p];
    float mx2; short8 h2f0, h2f1;
    post_layer(acc, bs2, hl, col, g, mx2, h2f0, h2f1);

    // ---- L3 (no relu): two independent 3-chains ----
#pragma unroll
    for (int p = 0; p < 16; ++p) { acc[p] = 0.0f; acc2[p] = 0.0f; }
    acc  = __builtin_amdgcn_mfma_f32_32x32x16_bf16(h2f0, wf[10], acc, 0, 0, 0);
    acc2 = __builtin_amdgcn_mfma_f32_32x32x16_bf16(h2f1, wf[11], acc2, 0, 0, 0);
    acc  = __builtin_amdgcn_mfma_f32_32x32x16_bf16(h1f0, wf[12], acc, 0, 0, 0);
    acc2 = __builtin_amdgcn_mfma_f32_32x32x16_bf16(h1f1, wf[13], acc2, 0, 0, 0);
    acc  = __builtin_amdgcn_mfma_f32_32x32x16_bf16(h0f0, wf[14], acc, 0, 0, 0);
    acc2 = __builtin_amdgcn_mfma_f32_32x32x16_bf16(h0f1, wf[15], acc2, 0, 0, 0);
    float m3 = (acc[0] + acc2[0]) + bs3;
#pragma unroll
    for (int p = 1; p < 16; ++p) m3 = fmaxf(m3, (acc[p] + acc2[p]) + bs3);
    m3 = fmaxf(m3, __shfl_xor(m3, 32));

    // ---- store: out row = [h3, h2, h1, h0, x] ----
    float* orow = out + (size_t)qs * 192;
    if (g == 0) {
        orow[col]      = m3;
        orow[32 + col] = mx2;
        orow[64 + col] = mx1;
        orow[96 + col] = mx0;
    }
    orow[128 + lane] = xq[lane];
}

extern "C" void kernel_launch(void* const* d_in, const int* in_sizes, int n_in,
                              void* d_out, int out_size, void* d_ws, size_t ws_size,
                              hipStream_t stream) {
    const float* x   = (const float*)d_in[0];
    const float* pos = (const float*)d_in[1];
    const float* Wf  = (const float*)d_in[2];
    const float* bf  = (const float*)d_in[3];
    const float* W1  = (const float*)d_in[4];
    const float* b1  = (const float*)d_in[5];
    const float* W2  = (const float*)d_in[6];
    const float* b2  = (const float*)d_in[7];
    const float* Wl  = (const float*)d_in[8];
    const float* bl  = (const float*)d_in[9];
    float* out = (float*)d_out;

    char* ws = (char*)d_ws;
    float*          wxt   = (float*)ws;                               // 32 KB
    float*          ballp = (float*)(ws + 32768);                     // 512 B
    unsigned short* wfrag = (unsigned short*)(ws + 40960);            // 16 KB
    unsigned short* xbf   = (unsigned short*)(ws + (1u << 20));       // 1 MB

    hipLaunchKernelGGL(prep_all_kernel, dim3(548), dim3(256), 0, stream,
                       x, Wf, W1, W2, Wl, bf, b1, b2, bl, xbf, wxt, ballp, wfrag);
    hipLaunchKernelGGL(fused_kernel, dim3(2048), dim3(256), 0, stream,
                       x, pos, xbf, wfrag, wxt, ballp, out);
}

// Round 6
// 46.746 us; speedup vs baseline: 4.7224x; 1.0535x over previous
//
#include <hip/hip_runtime.h>
#include <hip/hip_bf16.h>

#define NB 4
#define NN 2048
#define KK 32
#define DD 64
#define R2C 0.64f

typedef __attribute__((ext_vector_type(8)))  short short8;   // 8 bf16 (4 VGPRs)
typedef __attribute__((ext_vector_type(16))) float f32x16;   // 32x32 MFMA acc

__device__ __forceinline__ unsigned short f2bf(float f) {
    __hip_bfloat16 h = __float2bfloat16(f);
    return reinterpret_cast<unsigned short&>(h);
}

// ---------------- single prep kernel: xbf | wxt+ball | wfrag ----------------
// blocks [0,512): x->bf16; [512,544): wxt[128][64]+ball[128]; [544,548): wfrag
__global__ __launch_bounds__(256) void prep_all_kernel(const float* __restrict__ x,
                                                       const float* __restrict__ Wf,
                                                       const float* __restrict__ W1,
                                                       const float* __restrict__ W2,
                                                       const float* __restrict__ Wl,
                                                       const float* __restrict__ bf,
                                                       const float* __restrict__ b1,
                                                       const float* __restrict__ b2,
                                                       const float* __restrict__ bl,
                                                       unsigned short* __restrict__ xbf,
                                                       float* __restrict__ wxt,
                                                       float* __restrict__ ball,
                                                       unsigned short* __restrict__ wfrag) {
    int blk = blockIdx.x;
    if (blk < 512) {
        int t = blk * 256 + threadIdx.x;          // 131072 threads x 4 elems
        float4 v = ((const float4*)x)[t];
        ushort4 o = make_ushort4(f2bf(v.x), f2bf(v.y), f2bf(v.z), f2bf(v.w));
        *(ushort4*)(xbf + 4 * (size_t)t) = o;
    } else if (blk < 544) {
        int t = (blk - 512) * 256 + threadIdx.x;  // 8192 = 128 ch x 64 j
        int ch = t >> 6, j = t & 63;
        int L = ch >> 5, c = ch & 31;
        float v;
        if (L == 0)      v = Wf[j * 32 + c] - Wf[(128 + j) * 32 + c];
        else if (L == 1) v = W1[(32 + j) * 32 + c];
        else if (L == 2) v = W2[(64 + j) * 32 + c];
        else             v = Wl[(96 + j) * 32 + c];
        wxt[ch * 64 + j] = v;
        if (j == 0) ball[ch] = (L == 0 ? bf[c] : L == 1 ? b1[c] : L == 2 ? b2[c] : bl[c]);
    } else {
        int t = (blk - 544) * 256 + threadIdx.x;  // 1024
        int f = t >> 6, l = t & 63;
        int c = l & 31, g = l >> 5;
        unsigned short* dst = wfrag + (size_t)(f * 64 + l) * 8;
#pragma unroll
        for (int j = 0; j < 8; ++j) {
            int kl = 8 * g + j;
            float v;
            if (f < 4)       { int rr = 16 * f + kl;             v = Wf[(64 + rr) * 32 + c] + Wf[(128 + rr) * 32 + c]; }
            else if (f < 6)  { int rr = 16 * (f - 4) + kl;       v = W1[rr * 32 + c]; }
            else if (f < 8)  { int rr = 16 * (f - 6) + kl;       v = W2[rr * 32 + c]; }
            else if (f < 10) { int rr = 32 + 16 * (f - 8) + kl;  v = W2[rr * 32 + c]; }
            else if (f < 12) { int rr = 16 * (f - 10) + kl;      v = Wl[rr * 32 + c]; }
            else if (f < 14) { int rr = 32 + 16 * (f - 12) + kl; v = Wl[rr * 32 + c]; }
            else             { int rr = 64 + 16 * (f - 14) + kl; v = Wl[rr * 32 + c]; }
            dst[j] = f2bf(v);
        }
    }
}

// ---------------- fused main: ball query + bases + MFMA MLP + row-max ----------------
// D/C layout (verified): col = lane&31, row = (reg&3) + 8*(reg>>2) + 4*(lane>>5).
#define HSTRIDE 40   // ushorts per h-row in LDS (80B, 16B-aligned)

__device__ __forceinline__ void post_layer(const f32x16& acc, float bs,
                                           unsigned short* hl, int col, int g,
                                           float& mx, short8& f0, short8& f1) {
    float v[16];
#pragma unroll
    for (int p = 0; p < 16; ++p) v[p] = fmaxf(acc[p] + bs, 0.0f);   // base + relu
    float m = v[0];
#pragma unroll
    for (int p = 1; p < 16; ++p) m = fmaxf(m, v[p]);
    m = fmaxf(m, __shfl_xor(m, 32));     // combine wave halves
    mx = m;
#pragma unroll
    for (int p = 0; p < 16; ++p) {
        int r = (p & 3) + 8 * (p >> 2) + 4 * g;
        hl[r * HSTRIDE + col] = f2bf(v[p]);
    }
    const unsigned short* row = hl + col * HSTRIDE;
    f0 = *(const short8*)(row + 8 * g);
    f1 = *(const short8*)(row + 16 + 8 * g);
}

__global__ __launch_bounds__(256) void fused_kernel(const float* __restrict__ x,
                                                    const float* __restrict__ pos,
                                                    const unsigned short* __restrict__ xbf,
                                                    const unsigned short* __restrict__ wfrag,
                                                    const float* __restrict__ wxt,
                                                    const float* __restrict__ ball,
                                                    float* __restrict__ out) {
    __shared__ unsigned short hlds[4][32 * HSTRIDE];
    __shared__ int nbrs[4][KK];
    __shared__ unsigned short lwf[16 * 64 * 8];   // 16 KB weight fragments
    int wid = threadIdx.x >> 6, lane = threadIdx.x & 63;
    int qs = __builtin_amdgcn_readfirstlane(blockIdx.x * 4 + wid);  // one query per wave
    int col = lane & 31, g = lane >> 5;
    int b = qs >> 11, n = qs & (NN - 1);
    unsigned short* hl = hlds[wid];
    int* nbr = nbrs[wid];

    // ---- stage weight fragments to LDS (block-cooperative; barrier after scan) ----
    {
        const float4* src = (const float4*)wfrag;
        float4* dst = (float4*)lwf;
#pragma unroll
        for (int i = 0; i < 4; ++i) dst[threadIdx.x + 256 * i] = src[threadIdx.x + 256 * i];
    }

    // ---- fused bases: lane computes channels (lane) and (64+lane); x row wave-uniform ----
    const float* xq = x + (size_t)qs * DD;
    float accA = ball[lane];
    float accB = ball[64 + lane];
    const float4* wA = (const float4*)(wxt + (size_t)lane * DD);
    const float4* wB = (const float4*)(wxt + (size_t)(64 + lane) * DD);
#pragma unroll
    for (int j0 = 0; j0 < 16; ++j0) {
        float4 a4 = wA[j0], b4 = wB[j0];
        float x0 = xq[4 * j0], x1 = xq[4 * j0 + 1], x2 = xq[4 * j0 + 2], x3 = xq[4 * j0 + 3];
        accA = fmaf(x0, a4.x, accA); accA = fmaf(x1, a4.y, accA);
        accA = fmaf(x2, a4.z, accA); accA = fmaf(x3, a4.w, accA);
        accB = fmaf(x0, b4.x, accB); accB = fmaf(x1, b4.y, accB);
        accB = fmaf(x2, b4.z, accB); accB = fmaf(x3, b4.w, accB);
    }
    float bs0 = __shfl(accA, col, 64);
    float bs1 = __shfl(accA, 32 + col, 64);
    float bs2 = __shfl(accB, col, 64);
    float bs3 = __shfl(accB, 32 + col, 64);

    // ---- in-wave ball query: chunked scan, 64 candidates per iteration ----
    // d2 arithmetic identical to reference: (sq[n]+sq[m]) - 2*dot, no contraction.
    const float* pb = pos + (size_t)b * NN * 3;
    float qx = pb[3 * n], qy = pb[3 * n + 1], qz = pb[3 * n + 2];
    float sqn = __fadd_rn(__fadd_rn(__fmul_rn(qx, qx), __fmul_rn(qy, qy)), __fmul_rn(qz, qz));
    int cnt = 0;
    for (int m0 = 0; m0 < NN && cnt < KK; m0 += 64) {
        int m = m0 + lane;
        float mx3 = pb[3 * m], my3 = pb[3 * m + 1], mz3 = pb[3 * m + 2];
        float sqm = __fadd_rn(__fadd_rn(__fmul_rn(mx3, mx3), __fmul_rn(my3, my3)), __fmul_rn(mz3, mz3));
        float dot = __fadd_rn(__fadd_rn(__fmul_rn(qx, mx3), __fmul_rn(qy, my3)), __fmul_rn(qz, mz3));
        float d2 = __fsub_rn(__fadd_rn(sqn, sqm), __fmul_rn(2.0f, dot));
        bool hit = d2 < R2C;
        unsigned long long mask = __ballot(hit);
        if (hit) {
            int p = cnt + (int)__popcll(mask & ((1ULL << lane) - 1ULL));
            if (p < KK) nbr[p] = m;
        }
        cnt = __builtin_amdgcn_readfirstlane(cnt + (int)__popcll(mask));
    }
    int nbn = nbr[col < cnt ? col : 0];      // pad with first hit

    // neighbor gather: lane's A-row = col (issue before barrier; waitcnt lands at L0)
    const short8* xrow = (const short8*)(xbf + (size_t)(b * NN + nbn) * DD + g * 8);
    short8 xk0 = xrow[0], xk1 = xrow[2], xk2 = xrow[4], xk3 = xrow[6];

    __syncthreads();     // lwf ready
    const short8* wl = (const short8*)lwf;

    // ---- L0: XK[32x64] @ w0k[64x32] ----
    f32x16 acc;
#pragma unroll
    for (int p = 0; p < 16; ++p) acc[p] = 0.0f;
    acc = __builtin_amdgcn_mfma_f32_32x32x16_bf16(xk0, wl[0 * 64 + lane], acc, 0, 0, 0);
    acc = __builtin_amdgcn_mfma_f32_32x32x16_bf16(xk1, wl[1 * 64 + lane], acc, 0, 0, 0);
    acc = __builtin_amdgcn_mfma_f32_32x32x16_bf16(xk2, wl[2 * 64 + lane], acc, 0, 0, 0);
    acc = __builtin_amdgcn_mfma_f32_32x32x16_bf16(xk3, wl[3 * 64 + lane], acc, 0, 0, 0);
    float mx0; short8 h0f0, h0f1;
    post_layer(acc, bs0, hl, col, g, mx0, h0f0, h0f1);

    // ---- L1 ----
#pragma unroll
    for (int p = 0; p < 16; ++p) acc[p] = 0.0f;
    acc = __builtin_amdgcn_mfma_f32_32x32x16_bf16(h0f0, wl[4 * 64 + lane], acc, 0, 0, 0);
    acc = __builtin_amdgcn_mfma_f32_32x32x16_bf16(h0f1, wl[5 * 64 + lane], acc, 0, 0, 0);
    float mx1; short8 h1f0, h1f1;
    post_layer(acc, bs1, hl, col, g, mx1, h1f0, h1f1);

    // ---- L2 ----
#pragma unroll
    for (int p = 0; p < 16; ++p) acc[p] = 0.0f;
    acc = __builtin_amdgcn_mfma_f32_32x32x16_bf16(h1f0, wl[6 * 64 + lane], acc, 0, 0, 0);
    acc = __builtin_amdgcn_mfma_f32_32x32x16_bf16(h1f1, wl[7 * 64 + lane], acc, 0, 0, 0);
    acc = __builtin_amdgcn_mfma_f32_32x32x16_bf16(h0f0, wl[8 * 64 + lane], acc, 0, 0, 0);
    acc = __builtin_amdgcn_mfma_f32_32x32x16_bf16(h0f1, wl[9 * 64 + lane], acc, 0, 0, 0);
    float mx2; short8 h2f0, h2f1;
    post_layer(acc, bs2, hl, col, g, mx2, h2f0, h2f1);

    // ---- L3 (no relu) ----
#pragma unroll
    for (int p = 0; p < 16; ++p) acc[p] = 0.0f;
    acc = __builtin_amdgcn_mfma_f32_32x32x16_bf16(h2f0, wl[10 * 64 + lane], acc, 0, 0, 0);
    acc = __builtin_amdgcn_mfma_f32_32x32x16_bf16(h2f1, wl[11 * 64 + lane], acc, 0, 0, 0);
    acc = __builtin_amdgcn_mfma_f32_32x32x16_bf16(h1f0, wl[12 * 64 + lane], acc, 0, 0, 0);
    acc = __builtin_amdgcn_mfma_f32_32x32x16_bf16(h1f1, wl[13 * 64 + lane], acc, 0, 0, 0);
    acc = __builtin_amdgcn_mfma_f32_32x32x16_bf16(h0f0, wl[14 * 64 + lane], acc, 0, 0, 0);
    acc = __builtin_amdgcn_mfma_f32_32x32x16_bf16(h0f1, wl[15 * 64 + lane], acc, 0, 0, 0);
    float m3 = acc[0] + bs3;
#pragma unroll
    for (int p = 1; p < 16; ++p) m3 = fmaxf(m3, acc[p] + bs3);
    m3 = fmaxf(m3, __shfl_xor(m3, 32));

    // ---- store: out row = [h3, h2, h1, h0, x] ----
    float* orow = out + (size_t)qs * 192;
    if (g == 0) {
        orow[col]      = m3;
        orow[32 + col] = mx2;
        orow[64 + col] = mx1;
        orow[96 + col] = mx0;
    }
    orow[128 + lane] = xq[lane];
}

extern "C" void kernel_launch(void* const* d_in, const int* in_sizes, int n_in,
                              void* d_out, int out_size, void* d_ws, size_t ws_size,
                              hipStream_t stream) {
    const float* x   = (const float*)d_in[0];
    const float* pos = (const float*)d_in[1];
    const float* Wf  = (const float*)d_in[2];
    const float* bf  = (const float*)d_in[3];
    const float* W1  = (const float*)d_in[4];
    const float* b1  = (const float*)d_in[5];
    const float* W2  = (const float*)d_in[6];
    const float* b2  = (const float*)d_in[7];
    const float* Wl  = (const float*)d_in[8];
    const float* bl  = (const float*)d_in[9];
    float* out = (float*)d_out;

    char* ws = (char*)d_ws;
    float*          wxt   = (float*)ws;                               // 32 KB
    float*          ballp = (float*)(ws + 32768);                     // 512 B
    unsigned short* wfrag = (unsigned short*)(ws + 40960);            // 16 KB
    unsigned short* xbf   = (unsigned short*)(ws + (1u << 20));       // 1 MB

    hipLaunchKernelGGL(prep_all_kernel, dim3(548), dim3(256), 0, stream,
                       x, Wf, W1, W2, Wl, bf, b1, b2, bl, xbf, wxt, ballp, wfrag);
    hipLaunchKernelGGL(fused_kernel, dim3(2048), dim3(256), 0, stream,
                       x, pos, xbf, wfrag, wxt, ballp, out);
}

// Round 7
// 33.599 us; speedup vs baseline: 6.5703x; 1.3913x over previous
//
#include <hip/hip_runtime.h>
#include <hip/hip_bf16.h>

#define NB 4
#define NN 2048
#define KK 32
#define DD 64
#define R2C 0.64f

typedef __attribute__((ext_vector_type(8)))  short short8;   // 8 bf16 (4 VGPRs)
typedef __attribute__((ext_vector_type(16))) float f32x16;   // 32x32 MFMA acc

__device__ __forceinline__ unsigned short f2bf(float f) {
    __hip_bfloat16 h = __float2bfloat16(f);
    return reinterpret_cast<unsigned short&>(h);
}

// ---------------- single prep kernel: xbf + out-x-tail | wxt+ball | wfrag ----------------
__global__ __launch_bounds__(256) void prep_all_kernel(const float* __restrict__ x,
                                                       const float* __restrict__ Wf,
                                                       const float* __restrict__ W1,
                                                       const float* __restrict__ W2,
                                                       const float* __restrict__ Wl,
                                                       const float* __restrict__ bf,
                                                       const float* __restrict__ b1,
                                                       const float* __restrict__ b2,
                                                       const float* __restrict__ bl,
                                                       unsigned short* __restrict__ xbf,
                                                       float* __restrict__ wxt,
                                                       float* __restrict__ ball,
                                                       unsigned short* __restrict__ wfrag,
                                                       float* __restrict__ out) {
    int blk = blockIdx.x;
    if (blk < 512) {
        int t = blk * 256 + threadIdx.x;          // 131072 threads x 4 elems
        float4 v = ((const float4*)x)[t];
        ushort4 o = make_ushort4(f2bf(v.x), f2bf(v.y), f2bf(v.z), f2bf(v.w));
        *(ushort4*)(xbf + 4 * (size_t)t) = o;
        // x passthrough: out[q][128+j..131] = x[q][j..j+3]  (max over k of x_tiled = x)
        int q = t >> 4, j = (t & 15) << 2;
        *(float4*)(out + (size_t)q * 192 + 128 + j) = v;
    } else if (blk < 544) {
        int t = (blk - 512) * 256 + threadIdx.x;  // 8192 = 128 ch x 64 j
        int ch = t >> 6, j = t & 63;
        int L = ch >> 5, c = ch & 31;
        float v;
        if (L == 0)      v = Wf[j * 32 + c] - Wf[(128 + j) * 32 + c];
        else if (L == 1) v = W1[(32 + j) * 32 + c];
        else if (L == 2) v = W2[(64 + j) * 32 + c];
        else             v = Wl[(96 + j) * 32 + c];
        wxt[ch * 64 + j] = v;
        if (j == 0) ball[ch] = (L == 0 ? bf[c] : L == 1 ? b1[c] : L == 2 ? b2[c] : bl[c]);
    } else {
        int t = (blk - 544) * 256 + threadIdx.x;  // 1024
        int f = t >> 6, l = t & 63;
        int c = l & 31, g = l >> 5;
        unsigned short* dst = wfrag + (size_t)(f * 64 + l) * 8;
#pragma unroll
        for (int j = 0; j < 8; ++j) {
            int kl = 8 * g + j;
            float v;
            if (f < 4)       { int rr = 16 * f + kl;             v = Wf[(64 + rr) * 32 + c] + Wf[(128 + rr) * 32 + c]; }
            else if (f < 6)  { int rr = 16 * (f - 4) + kl;       v = W1[rr * 32 + c]; }
            else if (f < 8)  { int rr = 16 * (f - 6) + kl;       v = W2[rr * 32 + c]; }
            else if (f < 10) { int rr = 32 + 16 * (f - 8) + kl;  v = W2[rr * 32 + c]; }
            else if (f < 12) { int rr = 16 * (f - 10) + kl;      v = Wl[rr * 32 + c]; }
            else if (f < 14) { int rr = 32 + 16 * (f - 12) + kl; v = Wl[rr * 32 + c]; }
            else             { int rr = 64 + 16 * (f - 14) + kl; v = Wl[rr * 32 + c]; }
            dst[j] = f2bf(v);
        }
    }
}

// ---------------- fused main: 2 queries per wave, interleaved chains ----------------
// D/C layout (verified): col = lane&31, row = (reg&3) + 8*(reg>>2) + 4*(lane>>5).
#define HSTRIDE 40   // ushorts per h-row in LDS (80B = 5x16B, b128-aligned)

// dual post-layer: relu+max+LDS-transpose for two queries sharing one lgkm wait
__device__ __forceinline__ void post2(const f32x16& a0, const f32x16& a1,
                                      float b0, float b1,
                                      unsigned short* l0, unsigned short* l1,
                                      int col, int g, float* mx, short8* hf0, short8* hf1) {
    float v0[16], v1[16];
#pragma unroll
    for (int p = 0; p < 16; ++p) { v0[p] = fmaxf(a0[p] + b0, 0.0f); v1[p] = fmaxf(a1[p] + b1, 0.0f); }
    float m0 = v0[0], m1 = v1[0];
#pragma unroll
    for (int p = 1; p < 16; ++p) { m0 = fmaxf(m0, v0[p]); m1 = fmaxf(m1, v1[p]); }
    mx[0] = fmaxf(m0, __shfl_xor(m0, 32));
    mx[1] = fmaxf(m1, __shfl_xor(m1, 32));
#pragma unroll
    for (int p = 0; p < 16; ++p) {
        int r = (p & 3) + 8 * (p >> 2) + 4 * g;
        l0[r * HSTRIDE + col] = f2bf(v0[p]);
        l1[r * HSTRIDE + col] = f2bf(v1[p]);
    }
    const unsigned short* row0 = l0 + col * HSTRIDE;
    const unsigned short* row1 = l1 + col * HSTRIDE;
    hf0[0] = *(const short8*)(row0 + 8 * g);
    hf0[1] = *(const short8*)(row0 + 16 + 8 * g);
    hf1[0] = *(const short8*)(row1 + 8 * g);
    hf1[1] = *(const short8*)(row1 + 16 + 8 * g);
}

__global__ __launch_bounds__(256) void fused_kernel(const float* __restrict__ x,
                                                    const float* __restrict__ pos,
                                                    const unsigned short* __restrict__ xbf,
                                                    const unsigned short* __restrict__ wfrag,
                                                    const float* __restrict__ wxt,
                                                    const float* __restrict__ ball,
                                                    float* __restrict__ out) {
    __shared__ unsigned short hlds[4][2][32 * HSTRIDE];
    __shared__ int nbrs[4][2][KK];
    __shared__ unsigned short lwf[16 * 64 * 8];   // 16 KB weight fragments
    int wid = threadIdx.x >> 6, lane = threadIdx.x & 63;
    int qp = __builtin_amdgcn_readfirstlane(blockIdx.x * 4 + wid);  // pair index [0,4096)
    int q0 = qp << 1;                               // even; q0,q0+1 share batch
    int col = lane & 31, g = lane >> 5;
    int b = q0 >> 11, n0 = q0 & (NN - 1);

    // ---- stage weight fragments to LDS (block-cooperative; barrier later) ----
    {
        const float4* src = (const float4*)wfrag;
        float4* dst = (float4*)lwf;
#pragma unroll
        for (int i = 0; i < 4; ++i) dst[threadIdx.x + 256 * i] = src[threadIdx.x + 256 * i];
    }

    // ---- bases for both queries: shared weight loads, 4 independent FMA chains ----
    const float* xq0 = x + (size_t)q0 * DD;
    float aA0 = ball[lane], aB0 = ball[64 + lane];
    float aA1 = aA0, aB1 = aB0;
    const float4* wA = (const float4*)(wxt + (size_t)lane * DD);
    const float4* wB = (const float4*)(wxt + (size_t)(64 + lane) * DD);
#pragma unroll
    for (int j0 = 0; j0 < 16; ++j0) {
        float4 a4 = wA[j0], b4 = wB[j0];
        float p0 = xq0[4 * j0], p1 = xq0[4 * j0 + 1], p2 = xq0[4 * j0 + 2], p3 = xq0[4 * j0 + 3];
        float r0 = xq0[DD + 4 * j0], r1 = xq0[DD + 4 * j0 + 1], r2 = xq0[DD + 4 * j0 + 2], r3 = xq0[DD + 4 * j0 + 3];
        aA0 = fmaf(p0, a4.x, aA0); aA0 = fmaf(p1, a4.y, aA0); aA0 = fmaf(p2, a4.z, aA0); aA0 = fmaf(p3, a4.w, aA0);
        aB0 = fmaf(p0, b4.x, aB0); aB0 = fmaf(p1, b4.y, aB0); aB0 = fmaf(p2, b4.z, aB0); aB0 = fmaf(p3, b4.w, aB0);
        aA1 = fmaf(r0, a4.x, aA1); aA1 = fmaf(r1, a4.y, aA1); aA1 = fmaf(r2, a4.z, aA1); aA1 = fmaf(r3, a4.w, aA1);
        aB1 = fmaf(r0, b4.x, aB1); aB1 = fmaf(r1, b4.y, aB1); aB1 = fmaf(r2, b4.z, aB1); aB1 = fmaf(r3, b4.w, aB1);
    }
    float bsv0[4] = { __shfl(aA0, col, 64), __shfl(aA0, 32 + col, 64),
                      __shfl(aB0, col, 64), __shfl(aB0, 32 + col, 64) };
    float bsv1[4] = { __shfl(aA1, col, 64), __shfl(aA1, 32 + col, 64),
                      __shfl(aB1, col, 64), __shfl(aB1, 32 + col, 64) };

    // ---- in-wave ball query for both queries (exact reference arithmetic) ----
    const float* pb = pos + (size_t)b * NN * 3;
    int nbn[2];
#pragma unroll
    for (int t = 0; t < 2; ++t) {
        int n = n0 + t;
        float qx = pb[3 * n], qy = pb[3 * n + 1], qz = pb[3 * n + 2];
        float sqn = __fadd_rn(__fadd_rn(__fmul_rn(qx, qx), __fmul_rn(qy, qy)), __fmul_rn(qz, qz));
        int* nbr = nbrs[wid][t];
        int cnt = 0;
        for (int m0 = 0; m0 < NN && cnt < KK; m0 += 64) {
            int m = m0 + lane;
            float mx3 = pb[3 * m], my3 = pb[3 * m + 1], mz3 = pb[3 * m + 2];
            float sqm = __fadd_rn(__fadd_rn(__fmul_rn(mx3, mx3), __fmul_rn(my3, my3)), __fmul_rn(mz3, mz3));
            float dot = __fadd_rn(__fadd_rn(__fmul_rn(qx, mx3), __fmul_rn(qy, my3)), __fmul_rn(qz, mz3));
            float d2 = __fsub_rn(__fadd_rn(sqn, sqm), __fmul_rn(2.0f, dot));
            bool hit = d2 < R2C;
            unsigned long long mask = __ballot(hit);
            if (hit) {
                int p = cnt + (int)__popcll(mask & ((1ULL << lane) - 1ULL));
                if (p < KK) nbr[p] = m;
            }
            cnt = __builtin_amdgcn_readfirstlane(cnt + (int)__popcll(mask));
        }
        nbn[t] = nbr[col < cnt ? col : 0];      // pad with first hit
    }

    // ---- gather both queries' neighbor rows ----
    short8 xk[2][4];
#pragma unroll
    for (int t = 0; t < 2; ++t) {
        const short8* xrow = (const short8*)(xbf + (size_t)(b * NN + nbn[t]) * DD + g * 8);
        xk[t][0] = xrow[0]; xk[t][1] = xrow[2]; xk[t][2] = xrow[4]; xk[t][3] = xrow[6];
    }

    __syncthreads();     // lwf ready
    const short8* wl = (const short8*)lwf;
    unsigned short* hl0 = hlds[wid][0];
    unsigned short* hl1 = hlds[wid][1];

    f32x16 ac0, ac1;
    float mx0[2], mx1[2], mx2[2];
    short8 h0f[2][2], h1f[2][2], h2f[2][2];

    // ---- L0 ----
#pragma unroll
    for (int p = 0; p < 16; ++p) { ac0[p] = 0.0f; ac1[p] = 0.0f; }
#pragma unroll
    for (int f = 0; f < 4; ++f) {
        short8 wv = wl[f * 64 + lane];
        ac0 = __builtin_amdgcn_mfma_f32_32x32x16_bf16(xk[0][f], wv, ac0, 0, 0, 0);
        ac1 = __builtin_amdgcn_mfma_f32_32x32x16_bf16(xk[1][f], wv, ac1, 0, 0, 0);
    }
    post2(ac0, ac1, bsv0[0], bsv1[0], hl0, hl1, col, g, mx0, h0f[0], h0f[1]);

    // ---- L1 ----
#pragma unroll
    for (int p = 0; p < 16; ++p) { ac0[p] = 0.0f; ac1[p] = 0.0f; }
#pragma unroll
    for (int f = 0; f < 2; ++f) {
        short8 wv = wl[(4 + f) * 64 + lane];
        ac0 = __builtin_amdgcn_mfma_f32_32x32x16_bf16(h0f[0][f], wv, ac0, 0, 0, 0);
        ac1 = __builtin_amdgcn_mfma_f32_32x32x16_bf16(h0f[1][f], wv, ac1, 0, 0, 0);
    }
    post2(ac0, ac1, bsv0[1], bsv1[1], hl0, hl1, col, g, mx1, h1f[0], h1f[1]);

    // ---- L2 ----
#pragma unroll
    for (int p = 0; p < 16; ++p) { ac0[p] = 0.0f; ac1[p] = 0.0f; }
#pragma unroll
    for (int f = 0; f < 2; ++f) {
        short8 wv = wl[(6 + f) * 64 + lane];
        ac0 = __builtin_amdgcn_mfma_f32_32x32x16_bf16(h1f[0][f], wv, ac0, 0, 0, 0);
        ac1 = __builtin_amdgcn_mfma_f32_32x32x16_bf16(h1f[1][f], wv, ac1, 0, 0, 0);
    }
#pragma unroll
    for (int f = 0; f < 2; ++f) {
        short8 wv = wl[(8 + f) * 64 + lane];
        ac0 = __builtin_amdgcn_mfma_f32_32x32x16_bf16(h0f[0][f], wv, ac0, 0, 0, 0);
        ac1 = __builtin_amdgcn_mfma_f32_32x32x16_bf16(h0f[1][f], wv, ac1, 0, 0, 0);
    }
    post2(ac0, ac1, bsv0[2], bsv1[2], hl0, hl1, col, g, mx2, h2f[0], h2f[1]);

    // ---- L3 (no relu) ----
#pragma unroll
    for (int p = 0; p < 16; ++p) { ac0[p] = 0.0f; ac1[p] = 0.0f; }
#pragma unroll
    for (int f = 0; f < 2; ++f) {
        short8 wv = wl[(10 + f) * 64 + lane];
        ac0 = __builtin_amdgcn_mfma_f32_32x32x16_bf16(h2f[0][f], wv, ac0, 0, 0, 0);
        ac1 = __builtin_amdgcn_mfma_f32_32x32x16_bf16(h2f[1][f], wv, ac1, 0, 0, 0);
    }
#pragma unroll
    for (int f = 0; f < 2; ++f) {
        short8 wv = wl[(12 + f) * 64 + lane];
        ac0 = __builtin_amdgcn_mfma_f32_32x32x16_bf16(h1f[0][f], wv, ac0, 0, 0, 0);
        ac1 = __builtin_amdgcn_mfma_f32_32x32x16_bf16(h1f[1][f], wv, ac1, 0, 0, 0);
    }
#pragma unroll
    for (int f = 0; f < 2; ++f) {
        short8 wv = wl[(14 + f) * 64 + lane];
        ac0 = __builtin_amdgcn_mfma_f32_32x32x16_bf16(h0f[0][f], wv, ac0, 0, 0, 0);
        ac1 = __builtin_amdgcn_mfma_f32_32x32x16_bf16(h0f[1][f], wv, ac1, 0, 0, 0);
    }
    float m30 = ac0[0] + bsv0[3], m31 = ac1[0] + bsv1[3];
#pragma unroll
    for (int p = 1; p < 16; ++p) { m30 = fmaxf(m30, ac0[p] + bsv0[3]); m31 = fmaxf(m31, ac1[p] + bsv1[3]); }
    m30 = fmaxf(m30, __shfl_xor(m30, 32));
    m31 = fmaxf(m31, __shfl_xor(m31, 32));

    // ---- store: out rows = [h3, h2, h1, h0] (x tail written by prep) ----
    if (g == 0) {
        float* o0 = out + (size_t)q0 * 192;
        o0[col]      = m30;
        o0[32 + col] = mx2[0];
        o0[64 + col] = mx1[0];
        o0[96 + col] = mx0[0];
        float* o1 = o0 + 192;
        o1[col]      = m31;
        o1[32 + col] = mx2[1];
        o1[64 + col] = mx1[1];
        o1[96 + col] = mx0[1];
    }
}

extern "C" void kernel_launch(void* const* d_in, const int* in_sizes, int n_in,
                              void* d_out, int out_size, void* d_ws, size_t ws_size,
                              hipStream_t stream) {
    const float* x   = (const float*)d_in[0];
    const float* pos = (const float*)d_in[1];
    const float* Wf  = (const float*)d_in[2];
    const float* bf  = (const float*)d_in[3];
    const float* W1  = (const float*)d_in[4];
    const float* b1  = (const float*)d_in[5];
    const float* W2  = (const float*)d_in[6];
    const float* b2  = (const float*)d_in[7];
    const float* Wl  = (const float*)d_in[8];
    const float* bl  = (const float*)d_in[9];
    float* out = (float*)d_out;

    char* ws = (char*)d_ws;
    float*          wxt   = (float*)ws;                               // 32 KB
    float*          ballp = (float*)(ws + 32768);                     // 512 B
    unsigned short* wfrag = (unsigned short*)(ws + 40960);            // 16 KB
    unsigned short* xbf   = (unsigned short*)(ws + (1u << 20));       // 1 MB

    hipLaunchKernelGGL(prep_all_kernel, dim3(548), dim3(256), 0, stream,
                       x, Wf, W1, W2, Wl, bf, b1, b2, bl, xbf, wxt, ballp, wfrag, out);
    hipLaunchKernelGGL(fused_kernel, dim3(1024), dim3(256), 0, stream,
                       x, pos, xbf, wfrag, wxt, ballp, out);
}

// Round 8
// 27.848 us; speedup vs baseline: 7.9273x; 1.2065x over previous
//
#include <hip/hip_runtime.h>
#include <hip/hip_bf16.h>

#define NB 4
#define NN 2048
#define KK 32
#define DD 64
#define R2C 0.64f

typedef __attribute__((ext_vector_type(8)))  short short8;   // 8 bf16 (4 VGPRs)
typedef __attribute__((ext_vector_type(16))) float f32x16;   // 32x32 MFMA acc

__device__ __forceinline__ unsigned short f2bf(float f) {
    __hip_bfloat16 h = __float2bfloat16(f);
    return reinterpret_cast<unsigned short&>(h);
}

// ---------------- single prep kernel: xbf + out-x-tail | wxt+ball | wfrag ----------------
__global__ __launch_bounds__(256) void prep_all_kernel(const float* __restrict__ x,
                                                       const float* __restrict__ Wf,
                                                       const float* __restrict__ W1,
                                                       const float* __restrict__ W2,
                                                       const float* __restrict__ Wl,
                                                       const float* __restrict__ bf,
                                                       const float* __restrict__ b1,
                                                       const float* __restrict__ b2,
                                                       const float* __restrict__ bl,
                                                       unsigned short* __restrict__ xbf,
                                                       float* __restrict__ wxt,
                                                       float* __restrict__ ball,
                                                       unsigned short* __restrict__ wfrag,
                                                       float* __restrict__ out) {
    int blk = blockIdx.x;
    if (blk < 512) {
        int t = blk * 256 + threadIdx.x;          // 131072 threads x 4 elems
        float4 v = ((const float4*)x)[t];
        ushort4 o = make_ushort4(f2bf(v.x), f2bf(v.y), f2bf(v.z), f2bf(v.w));
        *(ushort4*)(xbf + 4 * (size_t)t) = o;
        // x passthrough: out[q][128+j..j+3] = x[q][j..j+3]
        int q = t >> 4, j = (t & 15) << 2;
        *(float4*)(out + (size_t)q * 192 + 128 + j) = v;
    } else if (blk < 544) {
        int t = (blk - 512) * 256 + threadIdx.x;  // 8192 = 128 ch x 64 j
        int ch = t >> 6, j = t & 63;
        int L = ch >> 5, c = ch & 31;
        float v;
        if (L == 0)      v = Wf[j * 32 + c] - Wf[(128 + j) * 32 + c];
        else if (L == 1) v = W1[(32 + j) * 32 + c];
        else if (L == 2) v = W2[(64 + j) * 32 + c];
        else             v = Wl[(96 + j) * 32 + c];
        wxt[ch * 64 + j] = v;
        if (j == 0) ball[ch] = (L == 0 ? bf[c] : L == 1 ? b1[c] : L == 2 ? b2[c] : bl[c]);
    } else {
        int t = (blk - 544) * 256 + threadIdx.x;  // 1024
        int f = t >> 6, l = t & 63;
        int c = l & 31, g = l >> 5;
        unsigned short* dst = wfrag + (size_t)(f * 64 + l) * 8;
#pragma unroll
        for (int j = 0; j < 8; ++j) {
            int kl = 8 * g + j;
            float v;
            if (f < 4)       { int rr = 16 * f + kl;             v = Wf[(64 + rr) * 32 + c] + Wf[(128 + rr) * 32 + c]; }
            else if (f < 6)  { int rr = 16 * (f - 4) + kl;       v = W1[rr * 32 + c]; }
            else if (f < 8)  { int rr = 16 * (f - 6) + kl;       v = W2[rr * 32 + c]; }
            else if (f < 10) { int rr = 32 + 16 * (f - 8) + kl;  v = W2[rr * 32 + c]; }
            else if (f < 12) { int rr = 16 * (f - 10) + kl;      v = Wl[rr * 32 + c]; }
            else if (f < 14) { int rr = 32 + 16 * (f - 12) + kl; v = Wl[rr * 32 + c]; }
            else             { int rr = 64 + 16 * (f - 14) + kl; v = Wl[rr * 32 + c]; }
            dst[j] = f2bf(v);
        }
    }
}

// ---------------- fused main: 4 queries per wave, interleaved chains ----------------
// D/C layout (verified): col = lane&31, row = (reg&3) + 8*(reg>>2) + 4*(lane>>5).
#define HSTRIDE 40   // ushorts per h-row in LDS (80B = 5x16B, b128-aligned)

__device__ __forceinline__ void post_layer(const f32x16& acc, float bs,
                                           unsigned short* hl, int col, int g,
                                           float& mx, short8& f0, short8& f1) {
    float v[16];
#pragma unroll
    for (int p = 0; p < 16; ++p) v[p] = fmaxf(acc[p] + bs, 0.0f);   // base + relu
    float m = v[0];
#pragma unroll
    for (int p = 1; p < 16; ++p) m = fmaxf(m, v[p]);
    mx = fmaxf(m, __shfl_xor(m, 32));
#pragma unroll
    for (int p = 0; p < 16; ++p) {
        int r = (p & 3) + 8 * (p >> 2) + 4 * g;
        hl[r * HSTRIDE + col] = f2bf(v[p]);
    }
    const unsigned short* row = hl + col * HSTRIDE;
    f0 = *(const short8*)(row + 8 * g);
    f1 = *(const short8*)(row + 16 + 8 * g);
}

__device__ __forceinline__ void l0_mfma(const unsigned short* __restrict__ xbf, int row,
                                        int g, int lane, const short8* wl, f32x16& acc) {
#pragma unroll
    for (int p = 0; p < 16; ++p) acc[p] = 0.0f;
    const short8* xrow = (const short8*)(xbf + (size_t)row * DD + g * 8);
    short8 k0 = xrow[0], k1 = xrow[2], k2 = xrow[4], k3 = xrow[6];
    acc = __builtin_amdgcn_mfma_f32_32x32x16_bf16(k0, wl[0 * 64 + lane], acc, 0, 0, 0);
    acc = __builtin_amdgcn_mfma_f32_32x32x16_bf16(k1, wl[1 * 64 + lane], acc, 0, 0, 0);
    acc = __builtin_amdgcn_mfma_f32_32x32x16_bf16(k2, wl[2 * 64 + lane], acc, 0, 0, 0);
    acc = __builtin_amdgcn_mfma_f32_32x32x16_bf16(k3, wl[3 * 64 + lane], acc, 0, 0, 0);
}

__device__ __forceinline__ void l1_mfma(const short8* hf, int lane, const short8* wl, f32x16& acc) {
#pragma unroll
    for (int p = 0; p < 16; ++p) acc[p] = 0.0f;
    acc = __builtin_amdgcn_mfma_f32_32x32x16_bf16(hf[0], wl[4 * 64 + lane], acc, 0, 0, 0);
    acc = __builtin_amdgcn_mfma_f32_32x32x16_bf16(hf[1], wl[5 * 64 + lane], acc, 0, 0, 0);
}

__device__ __forceinline__ void l2_mfma(const short8* h1, const short8* h0,
                                        int lane, const short8* wl, f32x16& acc) {
#pragma unroll
    for (int p = 0; p < 16; ++p) acc[p] = 0.0f;
    acc = __builtin_amdgcn_mfma_f32_32x32x16_bf16(h1[0], wl[6 * 64 + lane], acc, 0, 0, 0);
    acc = __builtin_amdgcn_mfma_f32_32x32x16_bf16(h1[1], wl[7 * 64 + lane], acc, 0, 0, 0);
    acc = __builtin_amdgcn_mfma_f32_32x32x16_bf16(h0[0], wl[8 * 64 + lane], acc, 0, 0, 0);
    acc = __builtin_amdgcn_mfma_f32_32x32x16_bf16(h0[1], wl[9 * 64 + lane], acc, 0, 0, 0);
}

__device__ __forceinline__ void l3_mfma(const short8* h2, const short8* h1, const short8* h0,
                                        int lane, const short8* wl, f32x16& acc) {
#pragma unroll
    for (int p = 0; p < 16; ++p) acc[p] = 0.0f;
    acc = __builtin_amdgcn_mfma_f32_32x32x16_bf16(h2[0], wl[10 * 64 + lane], acc, 0, 0, 0);
    acc = __builtin_amdgcn_mfma_f32_32x32x16_bf16(h2[1], wl[11 * 64 + lane], acc, 0, 0, 0);
    acc = __builtin_amdgcn_mfma_f32_32x32x16_bf16(h1[0], wl[12 * 64 + lane], acc, 0, 0, 0);
    acc = __builtin_amdgcn_mfma_f32_32x32x16_bf16(h1[1], wl[13 * 64 + lane], acc, 0, 0, 0);
    acc = __builtin_amdgcn_mfma_f32_32x32x16_bf16(h0[0], wl[14 * 64 + lane], acc, 0, 0, 0);
    acc = __builtin_amdgcn_mfma_f32_32x32x16_bf16(h0[1], wl[15 * 64 + lane], acc, 0, 0, 0);
}

__global__ __launch_bounds__(256, 2) void fused_kernel(const float* __restrict__ x,
                                                       const float* __restrict__ pos,
                                                       const unsigned short* __restrict__ xbf,
                                                       const unsigned short* __restrict__ wfrag,
                                                       const float* __restrict__ wxt,
                                                       const float* __restrict__ ball,
                                                       float* __restrict__ out) {
    __shared__ unsigned short hlds[4][4][32 * HSTRIDE];   // 40 KB
    __shared__ int nbrs[4][4][KK];                        // 2 KB
    __shared__ unsigned short lwf[16 * 64 * 8];           // 16 KB
    int wid = threadIdx.x >> 6, lane = threadIdx.x & 63;
    int qp = __builtin_amdgcn_readfirstlane(blockIdx.x * 4 + wid);  // quad index [0,2048)
    int q0 = qp << 2;                               // 4 queries share one batch (2048%4==0)
    int col = lane & 31, g = lane >> 5;
    int b = q0 >> 11, n0 = q0 & (NN - 1);

    // ---- stage weight fragments to LDS (block-cooperative; barrier later) ----
    {
        const float4* src = (const float4*)wfrag;
        float4* dst = (float4*)lwf;
#pragma unroll
        for (int i = 0; i < 4; ++i) dst[threadIdx.x + 256 * i] = src[threadIdx.x + 256 * i];
    }

    // ---- bases for 4 queries: shared weight loads, 8 independent FMA chains ----
    const float* xq0 = x + (size_t)q0 * DD;
    float balA = ball[lane], balB = ball[64 + lane];
    float aA[4] = {balA, balA, balA, balA};
    float aB[4] = {balB, balB, balB, balB};
    const float4* wA = (const float4*)(wxt + (size_t)lane * DD);
    const float4* wB = (const float4*)(wxt + (size_t)(64 + lane) * DD);
#pragma unroll
    for (int j0 = 0; j0 < 16; ++j0) {
        float4 a4 = wA[j0], b4 = wB[j0];
#pragma unroll
        for (int t = 0; t < 4; ++t) {
            const float* xr = xq0 + t * DD + 4 * j0;
            float x0 = xr[0], x1 = xr[1], x2 = xr[2], x3 = xr[3];
            aA[t] = fmaf(x0, a4.x, aA[t]); aA[t] = fmaf(x1, a4.y, aA[t]);
            aA[t] = fmaf(x2, a4.z, aA[t]); aA[t] = fmaf(x3, a4.w, aA[t]);
            aB[t] = fmaf(x0, b4.x, aB[t]); aB[t] = fmaf(x1, b4.y, aB[t]);
            aB[t] = fmaf(x2, b4.z, aB[t]); aB[t] = fmaf(x3, b4.w, aB[t]);
        }
    }
    float bs0[4], bs1[4], bs2[4], bs3[4];
#pragma unroll
    for (int t = 0; t < 4; ++t) {
        bs0[t] = __shfl(aA[t], col, 64); bs1[t] = __shfl(aA[t], 32 + col, 64);
        bs2[t] = __shfl(aB[t], col, 64); bs3[t] = __shfl(aB[t], 32 + col, 64);
    }

    // ---- shared-chunk ball query: one candidate load feeds 4 query tests ----
    // d2 arithmetic identical to reference: (sq[n]+sq[m]) - 2*dot, no contraction.
    const float* pb = pos + (size_t)b * NN * 3;
    float qxv[4], qyv[4], qzv[4], sq4[4];
#pragma unroll
    for (int t = 0; t < 4; ++t) {
        int n = n0 + t;
        qxv[t] = pb[3 * n]; qyv[t] = pb[3 * n + 1]; qzv[t] = pb[3 * n + 2];
        sq4[t] = __fadd_rn(__fadd_rn(__fmul_rn(qxv[t], qxv[t]), __fmul_rn(qyv[t], qyv[t])),
                           __fmul_rn(qzv[t], qzv[t]));
    }
    int cnt[4] = {0, 0, 0, 0};
    unsigned long long ltmask = (1ULL << lane) - 1ULL;
    for (int m0 = 0; m0 < NN; m0 += 64) {
        if (cnt[0] >= KK && cnt[1] >= KK && cnt[2] >= KK && cnt[3] >= KK) break;
        int m = m0 + lane;
        float mx3 = pb[3 * m], my3 = pb[3 * m + 1], mz3 = pb[3 * m + 2];
        float sqm = __fadd_rn(__fadd_rn(__fmul_rn(mx3, mx3), __fmul_rn(my3, my3)), __fmul_rn(mz3, mz3));
#pragma unroll
        for (int t = 0; t < 4; ++t) {
            if (cnt[t] < KK) {
                float dot = __fadd_rn(__fadd_rn(__fmul_rn(qxv[t], mx3), __fmul_rn(qyv[t], my3)),
                                      __fmul_rn(qzv[t], mz3));
                float d2 = __fsub_rn(__fadd_rn(sq4[t], sqm), __fmul_rn(2.0f, dot));
                bool hit = d2 < R2C;
                unsigned long long mask = __ballot(hit);
                if (hit) {
                    int p = cnt[t] + (int)__popcll(mask & ltmask);
                    if (p < KK) nbrs[wid][t][p] = m;
                }
                cnt[t] = __builtin_amdgcn_readfirstlane(cnt[t] + (int)__popcll(mask));
            }
        }
    }
    int nbn[4];
#pragma unroll
    for (int t = 0; t < 4; ++t) nbn[t] = nbrs[wid][t][col < cnt[t] ? col : 0];  // pad w/ first

    __syncthreads();     // lwf ready
    const short8* wl = (const short8*)lwf;
    unsigned short* hl0 = hlds[wid][0];
    unsigned short* hl1 = hlds[wid][1];
    unsigned short* hl2 = hlds[wid][2];
    unsigned short* hl3 = hlds[wid][3];

    f32x16 a0, a1, a2, a3;
    float mx0[4], mx1[4], mx2[4];
    short8 h0f[4][2], h1f[4][2], h2f[4][2];

    // ---- L0 (staggered mfma/post to bound live accumulators) ----
    l0_mfma(xbf, b * NN + nbn[0], g, lane, wl, a0);
    l0_mfma(xbf, b * NN + nbn[1], g, lane, wl, a1);
    post_layer(a0, bs0[0], hl0, col, g, mx0[0], h0f[0][0], h0f[0][1]);
    l0_mfma(xbf, b * NN + nbn[2], g, lane, wl, a2);
    post_layer(a1, bs0[1], hl1, col, g, mx0[1], h0f[1][0], h0f[1][1]);
    l0_mfma(xbf, b * NN + nbn[3], g, lane, wl, a3);
    post_layer(a2, bs0[2], hl2, col, g, mx0[2], h0f[2][0], h0f[2][1]);
    post_layer(a3, bs0[3], hl3, col, g, mx0[3], h0f[3][0], h0f[3][1]);

    // ---- L1 ----
    l1_mfma(h0f[0], lane, wl, a0);
    l1_mfma(h0f[1], lane, wl, a1);
    post_layer(a0, bs1[0], hl0, col, g, mx1[0], h1f[0][0], h1f[0][1]);
    l1_mfma(h0f[2], lane, wl, a2);
    post_layer(a1, bs1[1], hl1, col, g, mx1[1], h1f[1][0], h1f[1][1]);
    l1_mfma(h0f[3], lane, wl, a3);
    post_layer(a2, bs1[2], hl2, col, g, mx1[2], h1f[2][0], h1f[2][1]);
    post_layer(a3, bs1[3], hl3, col, g, mx1[3], h1f[3][0], h1f[3][1]);

    // ---- L2 ----
    l2_mfma(h1f[0], h0f[0], lane, wl, a0);
    l2_mfma(h1f[1], h0f[1], lane, wl, a1);
    post_layer(a0, bs2[0], hl0, col, g, mx2[0], h2f[0][0], h2f[0][1]);
    l2_mfma(h1f[2], h0f[2], lane, wl, a2);
    post_layer(a1, bs2[1], hl1, col, g, mx2[1], h2f[1][0], h2f[1][1]);
    l2_mfma(h1f[3], h0f[3], lane, wl, a3);
    post_layer(a2, bs2[2], hl2, col, g, mx2[2], h2f[2][0], h2f[2][1]);
    post_layer(a3, bs2[3], hl3, col, g, mx2[3], h2f[3][0], h2f[3][1]);

    // ---- L3 (no relu) ----
    float m3[4];
    l3_mfma(h2f[0], h1f[0], h0f[0], lane, wl, a0);
    l3_mfma(h2f[1], h1f[1], h0f[1], lane, wl, a1);
    {
        float m = a0[0] + bs3[0];
#pragma unroll
        for (int p = 1; p < 16; ++p) m = fmaxf(m, a0[p] + bs3[0]);
        m3[0] = fmaxf(m, __shfl_xor(m, 32));
    }
    l3_mfma(h2f[2], h1f[2], h0f[2], lane, wl, a2);
    {
        float m = a1[0] + bs3[1];
#pragma unroll
        for (int p = 1; p < 16; ++p) m = fmaxf(m, a1[p] + bs3[1]);
        m3[1] = fmaxf(m, __shfl_xor(m, 32));
    }
    l3_mfma(h2f[3], h1f[3], h0f[3], lane, wl, a3);
    {
        float m = a2[0] + bs3[2];
#pragma unroll
        for (int p = 1; p < 16; ++p) m = fmaxf(m, a2[p] + bs3[2]);
        m3[2] = fmaxf(m, __shfl_xor(m, 32));
    }
    {
        float m = a3[0] + bs3[3];
#pragma unroll
        for (int p = 1; p < 16; ++p) m = fmaxf(m, a3[p] + bs3[3]);
        m3[3] = fmaxf(m, __shfl_xor(m, 32));
    }

    // ---- store: out rows = [h3, h2, h1, h0] (x tail written by prep) ----
    if (g == 0) {
#pragma unroll
        for (int t = 0; t < 4; ++t) {
            float* o = out + (size_t)(q0 + t) * 192;
            o[col]      = m3[t];
            o[32 + col] = mx2[t];
            o[64 + col] = mx1[t];
            o[96 + col] = mx0[t];
        }
    }
}

extern "C" void kernel_launch(void* const* d_in, const int* in_sizes, int n_in,
                              void* d_out, int out_size, void* d_ws, size_t ws_size,
                              hipStream_t stream) {
    const float* x   = (const float*)d_in[0];
    const float* pos = (const float*)d_in[1];
    const float* Wf  = (const float*)d_in[2];
    const float* bf  = (const float*)d_in[3];
    const float* W1  = (const float*)d_in[4];
    const float* b1  = (const float*)d_in[5];
    const float* W2  = (const float*)d_in[6];
    const float* b2  = (const float*)d_in[7];
    const float* Wl  = (const float*)d_in[8];
    const float* bl  = (const float*)d_in[9];
    float* out = (float*)d_out;

    char* ws = (char*)d_ws;
    float*          wxt   = (float*)ws;                               // 32 KB
    float*          ballp = (float*)(ws + 32768);                     // 512 B
    unsigned short* wfrag = (unsigned short*)(ws + 40960);            // 16 KB
    unsigned short* xbf   = (unsigned short*)(ws + (1u << 20));       // 1 MB

    hipLaunchKernelGGL(prep_all_kernel, dim3(548), dim3(256), 0, stream,
                       x, Wf, W1, W2, Wl, bf, b1, b2, bl, xbf, wxt, ballp, wfrag, out);
    hipLaunchKernelGGL(fused_kernel, dim3(512), dim3(256), 0, stream,
                       x, pos, xbf, wfrag, wxt, ballp, out);
}

// Round 9
// 26.855 us; speedup vs baseline: 8.2203x; 1.0370x over previous
//
#include <hip/hip_runtime.h>
#include <hip/hip_bf16.h>

#define NB 4
#define NN 2048
#define KK 32
#define DD 64
#define R2C 0.64f

typedef __attribute__((ext_vector_type(8)))  short short8;   // 8 bf16 (4 VGPRs)
typedef __attribute__((ext_vector_type(16))) float f32x16;   // 32x32 MFMA acc

__device__ __forceinline__ unsigned short f2bf(float f) {
    __hip_bfloat16 h = __float2bfloat16(f);
    return reinterpret_cast<unsigned short&>(h);
}

// ---------------- single fused kernel: everything ----------------
// D/C layout (verified): col = lane&31, row = (reg&3) + 8*(reg>>2) + 4*(lane>>5).
#define HSTRIDE 40   // ushorts per h-row in LDS (80B = 5x16B, b128-aligned)

__device__ __forceinline__ void post_layer(const f32x16& acc, float bs,
                                           unsigned short* hl, int col, int g,
                                           float& mx, short8& f0, short8& f1) {
    float v[16];
#pragma unroll
    for (int p = 0; p < 16; ++p) v[p] = fmaxf(acc[p] + bs, 0.0f);   // base + relu
    float m = v[0];
#pragma unroll
    for (int p = 1; p < 16; ++p) m = fmaxf(m, v[p]);
    mx = fmaxf(m, __shfl_xor(m, 32));
#pragma unroll
    for (int p = 0; p < 16; ++p) {
        int r = (p & 3) + 8 * (p >> 2) + 4 * g;
        hl[r * HSTRIDE + col] = f2bf(v[p]);
    }
    const unsigned short* row = hl + col * HSTRIDE;
    f0 = *(const short8*)(row + 8 * g);
    f1 = *(const short8*)(row + 16 + 8 * g);
}

// gather 8 consecutive f32 and convert to a bf16 short8 fragment (RNE, same as prep did)
__device__ __forceinline__ short8 cvt8(const float* __restrict__ p) {
    float4 a = ((const float4*)p)[0];
    float4 b = ((const float4*)p)[1];
    short8 r;
    r[0] = (short)f2bf(a.x); r[1] = (short)f2bf(a.y); r[2] = (short)f2bf(a.z); r[3] = (short)f2bf(a.w);
    r[4] = (short)f2bf(b.x); r[5] = (short)f2bf(b.y); r[6] = (short)f2bf(b.z); r[7] = (short)f2bf(b.w);
    return r;
}

__device__ __forceinline__ void l1_mfma(const short8* hf, int lane, const short8* wl, f32x16& acc) {
#pragma unroll
    for (int p = 0; p < 16; ++p) acc[p] = 0.0f;
    acc = __builtin_amdgcn_mfma_f32_32x32x16_bf16(hf[0], wl[4 * 64 + lane], acc, 0, 0, 0);
    acc = __builtin_amdgcn_mfma_f32_32x32x16_bf16(hf[1], wl[5 * 64 + lane], acc, 0, 0, 0);
}

__device__ __forceinline__ void l2_mfma(const short8* h1, const short8* h0,
                                        int lane, const short8* wl, f32x16& acc) {
#pragma unroll
    for (int p = 0; p < 16; ++p) acc[p] = 0.0f;
    acc = __builtin_amdgcn_mfma_f32_32x32x16_bf16(h1[0], wl[6 * 64 + lane], acc, 0, 0, 0);
    acc = __builtin_amdgcn_mfma_f32_32x32x16_bf16(h1[1], wl[7 * 64 + lane], acc, 0, 0, 0);
    acc = __builtin_amdgcn_mfma_f32_32x32x16_bf16(h0[0], wl[8 * 64 + lane], acc, 0, 0, 0);
    acc = __builtin_amdgcn_mfma_f32_32x32x16_bf16(h0[1], wl[9 * 64 + lane], acc, 0, 0, 0);
}

__device__ __forceinline__ void l3_mfma(const short8* h2, const short8* h1, const short8* h0,
                                        int lane, const short8* wl, f32x16& acc) {
#pragma unroll
    for (int p = 0; p < 16; ++p) acc[p] = 0.0f;
    acc = __builtin_amdgcn_mfma_f32_32x32x16_bf16(h2[0], wl[10 * 64 + lane], acc, 0, 0, 0);
    acc = __builtin_amdgcn_mfma_f32_32x32x16_bf16(h2[1], wl[11 * 64 + lane], acc, 0, 0, 0);
    acc = __builtin_amdgcn_mfma_f32_32x32x16_bf16(h1[0], wl[12 * 64 + lane], acc, 0, 0, 0);
    acc = __builtin_amdgcn_mfma_f32_32x32x16_bf16(h1[1], wl[13 * 64 + lane], acc, 0, 0, 0);
    acc = __builtin_amdgcn_mfma_f32_32x32x16_bf16(h0[0], wl[14 * 64 + lane], acc, 0, 0, 0);
    acc = __builtin_amdgcn_mfma_f32_32x32x16_bf16(h0[1], wl[15 * 64 + lane], acc, 0, 0, 0);
}

__global__ __launch_bounds__(256, 2) void fused_kernel(const float* __restrict__ x,
                                                       const float* __restrict__ pos,
                                                       const float* __restrict__ Wf,
                                                       const float* __restrict__ bfv,
                                                       const float* __restrict__ W1,
                                                       const float* __restrict__ b1,
                                                       const float* __restrict__ W2,
                                                       const float* __restrict__ b2,
                                                       const float* __restrict__ Wl,
                                                       const float* __restrict__ bl,
                                                       float* __restrict__ out) {
    __shared__ unsigned short hlds[4][4][32 * HSTRIDE];   // 40 KB
    __shared__ int nbrs[4][4][KK];                        // 2 KB
    __shared__ unsigned short lwf[16 * 64 * 8];           // 16 KB
    int wid = threadIdx.x >> 6, lane = threadIdx.x & 63;
    int qp = __builtin_amdgcn_readfirstlane(blockIdx.x * 4 + wid);  // quad index [0,2048)
    int q0 = qp << 2;                               // 4 queries share one batch
    int col = lane & 31, g = lane >> 5;
    int b = q0 >> 11, n0 = q0 & (NN - 1);

    // ---- cooperative wfrag build into LDS (bf16 B-fragments, same math as old prep) ----
    // f0-3: w0k rows (Wf[64:128]+Wf[128:192]); f4-5: W1[0:32]; f6-9: W2[0:64]; f10-15: Wl[0:96]
    for (int e = threadIdx.x; e < 1024; e += 256) {
        int f = e >> 6, l = e & 63;
        int c = l & 31, g2 = l >> 5;
        unsigned short* dst = lwf + (size_t)(f * 64 + l) * 8;
#pragma unroll
        for (int j = 0; j < 8; ++j) {
            int kl = 8 * g2 + j;
            float v;
            if (f < 4)       { int rr = 16 * f + kl;             v = Wf[(64 + rr) * 32 + c] + Wf[(128 + rr) * 32 + c]; }
            else if (f < 6)  { int rr = 16 * (f - 4) + kl;       v = W1[rr * 32 + c]; }
            else if (f < 8)  { int rr = 16 * (f - 6) + kl;       v = W2[rr * 32 + c]; }
            else if (f < 10) { int rr = 32 + 16 * (f - 8) + kl;  v = W2[rr * 32 + c]; }
            else if (f < 12) { int rr = 16 * (f - 10) + kl;      v = Wl[rr * 32 + c]; }
            else if (f < 14) { int rr = 32 + 16 * (f - 12) + kl; v = Wl[rr * 32 + c]; }
            else             { int rr = 64 + 16 * (f - 14) + kl; v = Wl[rr * 32 + c]; }
            dst[j] = f2bf(v);
        }
    }

    // ---- bases from RAW weights (coalesced per half-wave), 8 independent FMA chains ----
    // lane ch mapping: accA -> ch=lane (L0: c=lane<32 / L1: c=lane-32), accB -> ch=64+lane (L2/L3)
    const float* xq0 = x + (size_t)q0 * DD;
    bool lo = lane < 32;
    int c0 = lane & 31;
    const float* pA1 = lo ? (Wf + c0) : (W1 + 32 * 32 + c0);     // w0x main / W1 x-part
    const float* pA2 = lo ? (Wf + 128 * 32 + c0) : (W1 + 32 * 32 + c0);  // subtracted term (dummy for hi)
    float sA = lo ? -1.0f : 0.0f;
    const float* pB1 = lo ? (W2 + 64 * 32 + c0) : (Wl + 96 * 32 + c0);
    float balA = lo ? bfv[c0] : b1[c0];
    float balB = lo ? b2[c0] : bl[c0];
    float aA[4] = {balA, balA, balA, balA};
    float aB[4] = {balB, balB, balB, balB};
#pragma unroll
    for (int j0 = 0; j0 < 16; ++j0) {
        float wa[4], wb[4];
#pragma unroll
        for (int jj = 0; jj < 4; ++jj) {
            int j = 4 * j0 + jj;
            wa[jj] = fmaf(sA, pA2[j * 32], pA1[j * 32]);   // lo: Wf[j][c]-Wf[128+j][c]; hi: W1[32+j][c]
            wb[jj] = pB1[j * 32];
        }
#pragma unroll
        for (int t = 0; t < 4; ++t) {
            const float* xr = xq0 + t * DD + 4 * j0;
            float x0 = xr[0], x1 = xr[1], x2 = xr[2], x3 = xr[3];
            aA[t] = fmaf(x0, wa[0], aA[t]); aA[t] = fmaf(x1, wa[1], aA[t]);
            aA[t] = fmaf(x2, wa[2], aA[t]); aA[t] = fmaf(x3, wa[3], aA[t]);
            aB[t] = fmaf(x0, wb[0], aB[t]); aB[t] = fmaf(x1, wb[1], aB[t]);
            aB[t] = fmaf(x2, wb[2], aB[t]); aB[t] = fmaf(x3, wb[3], aB[t]);
        }
    }
    float bs0[4], bs1[4], bs2[4], bs3[4];
#pragma unroll
    for (int t = 0; t < 4; ++t) {
        bs0[t] = __shfl(aA[t], col, 64); bs1[t] = __shfl(aA[t], 32 + col, 64);
        bs2[t] = __shfl(aB[t], col, 64); bs3[t] = __shfl(aB[t], 32 + col, 64);
    }

    // ---- shared-chunk ball query (exact reference arithmetic) ----
    const float* pb = pos + (size_t)b * NN * 3;
    float qxv[4], qyv[4], qzv[4], sq4[4];
#pragma unroll
    for (int t = 0; t < 4; ++t) {
        int n = n0 + t;
        qxv[t] = pb[3 * n]; qyv[t] = pb[3 * n + 1]; qzv[t] = pb[3 * n + 2];
        sq4[t] = __fadd_rn(__fadd_rn(__fmul_rn(qxv[t], qxv[t]), __fmul_rn(qyv[t], qyv[t])),
                           __fmul_rn(qzv[t], qzv[t]));
    }
    int cnt[4] = {0, 0, 0, 0};
    unsigned long long ltmask = (1ULL << lane) - 1ULL;
    for (int m0 = 0; m0 < NN; m0 += 64) {
        if (cnt[0] >= KK && cnt[1] >= KK && cnt[2] >= KK && cnt[3] >= KK) break;
        int m = m0 + lane;
        float mx3 = pb[3 * m], my3 = pb[3 * m + 1], mz3 = pb[3 * m + 2];
        float sqm = __fadd_rn(__fadd_rn(__fmul_rn(mx3, mx3), __fmul_rn(my3, my3)), __fmul_rn(mz3, mz3));
#pragma unroll
        for (int t = 0; t < 4; ++t) {
            if (cnt[t] < KK) {
                float dot = __fadd_rn(__fadd_rn(__fmul_rn(qxv[t], mx3), __fmul_rn(qyv[t], my3)),
                                      __fmul_rn(qzv[t], mz3));
                float d2 = __fsub_rn(__fadd_rn(sq4[t], sqm), __fmul_rn(2.0f, dot));
                bool hit = d2 < R2C;
                unsigned long long mask = __ballot(hit);
                if (hit) {
                    int p = cnt[t] + (int)__popcll(mask & ltmask);
                    if (p < KK) nbrs[wid][t][p] = m;
                }
                cnt[t] = __builtin_amdgcn_readfirstlane(cnt[t] + (int)__popcll(mask));
            }
        }
    }
    int nbn[4];
#pragma unroll
    for (int t = 0; t < 4; ++t) nbn[t] = nbrs[wid][t][col < cnt[t] ? col : 0];  // pad w/ first

    // ---- gather neighbor rows as f32, convert to bf16 fragments in-register ----
    short8 xk[4][4];
#pragma unroll
    for (int t = 0; t < 4; ++t) {
        const float* xrow = x + (size_t)(b * NN + nbn[t]) * DD + g * 8;
#pragma unroll
        for (int kf = 0; kf < 4; ++kf) xk[t][kf] = cvt8(xrow + kf * 16);
    }

    __syncthreads();     // lwf ready
    const short8* wl = (const short8*)lwf;
    unsigned short* hl0 = hlds[wid][0];
    unsigned short* hl1 = hlds[wid][1];
    unsigned short* hl2 = hlds[wid][2];
    unsigned short* hl3 = hlds[wid][3];

    f32x16 a0, a1, a2, a3;
    float mx0[4], mx1[4], mx2[4];
    short8 h0f[4][2], h1f[4][2], h2f[4][2];

    // ---- L0 (staggered mfma/post to bound live accumulators) ----
#pragma unroll
    for (int p = 0; p < 16; ++p) { a0[p] = 0.0f; a1[p] = 0.0f; a2[p] = 0.0f; a3[p] = 0.0f; }
#pragma unroll
    for (int f = 0; f < 4; ++f) a0 = __builtin_amdgcn_mfma_f32_32x32x16_bf16(xk[0][f], wl[f * 64 + lane], a0, 0, 0, 0);
#pragma unroll
    for (int f = 0; f < 4; ++f) a1 = __builtin_amdgcn_mfma_f32_32x32x16_bf16(xk[1][f], wl[f * 64 + lane], a1, 0, 0, 0);
    post_layer(a0, bs0[0], hl0, col, g, mx0[0], h0f[0][0], h0f[0][1]);
#pragma unroll
    for (int f = 0; f < 4; ++f) a2 = __builtin_amdgcn_mfma_f32_32x32x16_bf16(xk[2][f], wl[f * 64 + lane], a2, 0, 0, 0);
    post_layer(a1, bs0[1], hl1, col, g, mx0[1], h0f[1][0], h0f[1][1]);
#pragma unroll
    for (int f = 0; f < 4; ++f) a3 = __builtin_amdgcn_mfma_f32_32x32x16_bf16(xk[3][f], wl[f * 64 + lane], a3, 0, 0, 0);
    post_layer(a2, bs0[2], hl2, col, g, mx0[2], h0f[2][0], h0f[2][1]);
    post_layer(a3, bs0[3], hl3, col, g, mx0[3], h0f[3][0], h0f[3][1]);

    // ---- L1 ----
    l1_mfma(h0f[0], lane, wl, a0);
    l1_mfma(h0f[1], lane, wl, a1);
    post_layer(a0, bs1[0], hl0, col, g, mx1[0], h1f[0][0], h1f[0][1]);
    l1_mfma(h0f[2], lane, wl, a2);
    post_layer(a1, bs1[1], hl1, col, g, mx1[1], h1f[1][0], h1f[1][1]);
    l1_mfma(h0f[3], lane, wl, a3);
    post_layer(a2, bs1[2], hl2, col, g, mx1[2], h1f[2][0], h1f[2][1]);
    post_layer(a3, bs1[3], hl3, col, g, mx1[3], h1f[3][0], h1f[3][1]);

    // ---- L2 ----
    l2_mfma(h1f[0], h0f[0], lane, wl, a0);
    l2_mfma(h1f[1], h0f[1], lane, wl, a1);
    post_layer(a0, bs2[0], hl0, col, g, mx2[0], h2f[0][0], h2f[0][1]);
    l2_mfma(h1f[2], h0f[2], lane, wl, a2);
    post_layer(a1, bs2[1], hl1, col, g, mx2[1], h2f[1][0], h2f[1][1]);
    l2_mfma(h1f[3], h0f[3], lane, wl, a3);
    post_layer(a2, bs2[2], hl2, col, g, mx2[2], h2f[2][0], h2f[2][1]);
    post_layer(a3, bs2[3], hl3, col, g, mx2[3], h2f[3][0], h2f[3][1]);

    // ---- L3 (no relu) ----
    float m3[4];
    l3_mfma(h2f[0], h1f[0], h0f[0], lane, wl, a0);
    l3_mfma(h2f[1], h1f[1], h0f[1], lane, wl, a1);
    {
        float m = a0[0] + bs3[0];
#pragma unroll
        for (int p = 1; p < 16; ++p) m = fmaxf(m, a0[p] + bs3[0]);
        m3[0] = fmaxf(m, __shfl_xor(m, 32));
    }
    l3_mfma(h2f[2], h1f[2], h0f[2], lane, wl, a2);
    {
        float m = a1[0] + bs3[1];
#pragma unroll
        for (int p = 1; p < 16; ++p) m = fmaxf(m, a1[p] + bs3[1]);
        m3[1] = fmaxf(m, __shfl_xor(m, 32));
    }
    l3_mfma(h2f[3], h1f[3], h0f[3], lane, wl, a3);
    {
        float m = a2[0] + bs3[2];
#pragma unroll
        for (int p = 1; p < 16; ++p) m = fmaxf(m, a2[p] + bs3[2]);
        m3[2] = fmaxf(m, __shfl_xor(m, 32));
    }
    {
        float m = a3[0] + bs3[3];
#pragma unroll
        for (int p = 1; p < 16; ++p) m = fmaxf(m, a3[p] + bs3[3]);
        m3[3] = fmaxf(m, __shfl_xor(m, 32));
    }

    // ---- store: out rows = [h3, h2, h1, h0, x] ----
#pragma unroll
    for (int t = 0; t < 4; ++t) {
        float* o = out + (size_t)(q0 + t) * 192;
        if (g == 0) {
            o[col]      = m3[t];
            o[32 + col] = mx2[t];
            o[64 + col] = mx1[t];
            o[96 + col] = mx0[t];
        }
        o[128 + lane] = xq0[t * DD + lane];   // x passthrough (max over k of x_tiled = x)
    }
}

extern "C" void kernel_launch(void* const* d_in, const int* in_sizes, int n_in,
                              void* d_out, int out_size, void* d_ws, size_t ws_size,
                              hipStream_t stream) {
    const float* x   = (const float*)d_in[0];
    const float* pos = (const float*)d_in[1];
    const float* Wf  = (const float*)d_in[2];
    const float* bf  = (const float*)d_in[3];
    const float* W1  = (const float*)d_in[4];
    const float* b1  = (const float*)d_in[5];
    const float* W2  = (const float*)d_in[6];
    const float* b2  = (const float*)d_in[7];
    const float* Wl  = (const float*)d_in[8];
    const float* bl  = (const float*)d_in[9];
    float* out = (float*)d_out;

    hipLaunchKernelGGL(fused_kernel, dim3(512), dim3(256), 0, stream,
                       x, pos, Wf, bf, W1, b1, W2, b2, Wl, bl, out);
}